// Round 1
// baseline (376.998 us; speedup 1.0000x reference)
//
#include <hip/hip_runtime.h>
#include <hip/hip_bf16.h>
#include <cstdint>

#define DM 1024
#define DFF 4096
#define NB 2
#define TT 2048
#define NH 16
#define DH 64

typedef unsigned short u16;
typedef __bf16 bf16x8 __attribute__((ext_vector_type(8)));
typedef float f32x4 __attribute__((ext_vector_type(4)));

__device__ __forceinline__ u16 f2b(float f) {
    union { float f; unsigned u; } v; v.f = f;
    unsigned u = v.u;
    return (u16)((u + 0x7FFFu + ((u >> 16) & 1u)) >> 16);
}

__device__ __forceinline__ f32x4 mfma_bf16(bf16x8 a, bf16x8 b, f32x4 c) {
    return __builtin_amdgcn_mfma_f32_16x16x32_bf16(a, b, c, 0, 0, 0);
}

// ---------------- transpose + fp32->bf16 convert: Wt[n][k] = bf16(W[k][n]) ----------------
__global__ __launch_bounds__(256) void transW(const float* __restrict__ W, u16* __restrict__ Wt,
                                              int K, int N) {
    __shared__ float t[32][33];
    int tx = threadIdx.x & 31, ty = threadIdx.x >> 5;
    int k0 = blockIdx.y * 32, n0 = blockIdx.x * 32;
#pragma unroll
    for (int j = 0; j < 4; ++j)
        t[ty + 8 * j][tx] = W[(size_t)(k0 + ty + 8 * j) * N + n0 + tx];
    __syncthreads();
#pragma unroll
    for (int j = 0; j < 4; ++j)
        Wt[(size_t)(n0 + ty + 8 * j) * K + k0 + tx] = f2b(t[tx][ty + 8 * j]);
}

// ---------------- LayerNorm fp32 -> bf16 ----------------
__global__ __launch_bounds__(256) void ln_kernel(const float* __restrict__ X,
                                                 const float* __restrict__ g,
                                                 const float* __restrict__ bt,
                                                 u16* __restrict__ H) {
    int row = blockIdx.x, tid = threadIdx.x;
    float4 v = ((const float4*)(X + (size_t)row * DM))[tid];
    float s = v.x + v.y + v.z + v.w;
    float ss = v.x * v.x + v.y * v.y + v.z * v.z + v.w * v.w;
#pragma unroll
    for (int off = 32; off >= 1; off >>= 1) {
        s += __shfl_xor(s, off);
        ss += __shfl_xor(ss, off);
    }
    __shared__ float sb[8];
    int w = tid >> 6, lane = tid & 63;
    if (lane == 0) { sb[w] = s; sb[4 + w] = ss; }
    __syncthreads();
    s = sb[0] + sb[1] + sb[2] + sb[3];
    ss = sb[4] + sb[5] + sb[6] + sb[7];
    float mu = s * (1.0f / DM);
    float var = ss * (1.0f / DM) - mu * mu;
    float rstd = rsqrtf(var + 1e-5f);
    float4 gv = ((const float4*)g)[tid];
    float4 bv = ((const float4*)bt)[tid];
    ushort4 hv;
    hv.x = f2b((v.x - mu) * rstd * gv.x + bv.x);
    hv.y = f2b((v.y - mu) * rstd * gv.y + bv.y);
    hv.z = f2b((v.z - mu) * rstd * gv.z + bv.z);
    hv.w = f2b((v.w - mu) * rstd * gv.w + bv.w);
    ((ushort4*)(H + (size_t)row * DM))[tid] = hv;
}

// ---------------- bf16 MFMA GEMM: C[M,N] = A[M,K] @ Bt[N,K]^T, mode-specific epilogue ----------------
// MODE 0: scatter to q(scaled)/k/v [B,H,T,Dh] bf16
// MODE 1: outf = resid + C (fp32)
// MODE 2: outbf = gelu(C + bias) bf16
// MODE 3: outf = resid + C + bias (fp32)
template <int MODE>
__global__ __launch_bounds__(256) void gemm_kernel(
    const u16* __restrict__ A, const u16* __restrict__ Bt, int M, int N, int K,
    u16* __restrict__ oq, u16* __restrict__ ok, u16* __restrict__ ov,
    const float* __restrict__ resid, float* __restrict__ outf,
    const float* __restrict__ bias, u16* __restrict__ outbf) {
    __shared__ __align__(16) u16 Alds[128][72];
    __shared__ __align__(16) u16 Blds[128][72];
    const int tid = threadIdx.x;
    const int lane = tid & 63;
    const int w = tid >> 6;
    const int wr = w >> 1, wc = w & 1;
    const int bm = blockIdx.y * 128, bn = blockIdx.x * 128;
    const int l15 = lane & 15, lg = lane >> 4;

    f32x4 acc[4][4] = {};

    for (int k0 = 0; k0 < K; k0 += 64) {
#pragma unroll
        for (int i = 0; i < 4; ++i) {
            int idx = tid + 256 * i;
            int row = idx >> 3, ch = (idx & 7) * 8;
            *(uint4*)&Alds[row][ch] = *(const uint4*)(A + (size_t)(bm + row) * K + k0 + ch);
            *(uint4*)&Blds[row][ch] = *(const uint4*)(Bt + (size_t)(bn + row) * K + k0 + ch);
        }
        __syncthreads();
#pragma unroll
        for (int kk = 0; kk < 2; ++kk) {
            const int kc = kk * 32 + 8 * lg;
            bf16x8 af[4], bfr[4];
#pragma unroll
            for (int f = 0; f < 4; ++f) {
                af[f] = *(const bf16x8*)&Alds[wr * 64 + f * 16 + l15][kc];
                bfr[f] = *(const bf16x8*)&Blds[wc * 64 + f * 16 + l15][kc];
            }
#pragma unroll
            for (int mi = 0; mi < 4; ++mi)
#pragma unroll
                for (int ni = 0; ni < 4; ++ni)
                    acc[mi][ni] = mfma_bf16(af[mi], bfr[ni], acc[mi][ni]);
        }
        __syncthreads();
    }

    const int m0 = bm + wr * 64, n0 = bn + wc * 64;
#pragma unroll
    for (int mi = 0; mi < 4; ++mi) {
#pragma unroll
        for (int ni = 0; ni < 4; ++ni) {
#pragma unroll
            for (int r = 0; r < 4; ++r) {
                int m = m0 + mi * 16 + 4 * lg + r;
                int n = n0 + ni * 16 + l15;
                float v = acc[mi][ni][r];
                if constexpr (MODE == 0) {
                    int which = n >> 10, hh = (n >> 6) & 15, d = n & 63;
                    int b = m >> 11, t = m & 2047;
                    u16* dst = which == 0 ? oq : (which == 1 ? ok : ov);
                    if (which == 0) v *= 0.125f;  // 1/sqrt(DH)
                    dst[(((size_t)(b * NH + hh)) * TT + t) * DH + d] = f2b(v);
                } else if constexpr (MODE == 1) {
                    size_t o = (size_t)m * N + n;
                    outf[o] = resid[o] + v;
                } else if constexpr (MODE == 2) {
                    float z = v + bias[n];
                    outbf[(size_t)m * N + n] =
                        f2b(0.5f * z * (1.0f + erff(z * 0.70710678118654752f)));
                } else {
                    size_t o = (size_t)m * N + n;
                    outf[o] = resid[o] + v + bias[n];
                }
            }
        }
    }
}

// ---------------- flash attention, causal, bf16 MFMA ----------------
// grid: (T/128, B*H). 4 waves; wave w owns q rows [qt*128+w*32, +32)
__global__ __launch_bounds__(256) void attn_kernel(const u16* __restrict__ Q,
                                                   const u16* __restrict__ Kg,
                                                   const u16* __restrict__ Vg,
                                                   u16* __restrict__ O) {
    __shared__ __align__(16) u16 Klds[64][72];
    __shared__ __align__(16) u16 Vlds[64][72];  // transposed: Vlds[d][t]
    __shared__ __align__(16) u16 Plds[128][72]; // Q staging then per-wave P rows
    const int tid = threadIdx.x, lane = tid & 63, w = tid >> 6;
    const int l15 = lane & 15, lg = lane >> 4;
    const int qt = blockIdx.x, bh = blockIdx.y;
    const size_t base = (size_t)bh * TT * DH;

    // stage Q tile [128][64]
#pragma unroll
    for (int i = 0; i < 4; ++i) {
        int idx = tid + 256 * i;
        int row = idx >> 3, ch = (idx & 7) * 8;
        *(uint4*)&Plds[row][ch] = *(const uint4*)(Q + base + (size_t)(qt * 128 + row) * DH + ch);
    }
    __syncthreads();
    bf16x8 qf[2][2];
#pragma unroll
    for (int mf = 0; mf < 2; ++mf)
#pragma unroll
        for (int kf = 0; kf < 2; ++kf)
            qf[mf][kf] = *(const bf16x8*)&Plds[w * 32 + mf * 16 + l15][kf * 32 + 8 * lg];

    f32x4 o[2][4] = {};
    float mrun[2][4], lrun[2][4];
#pragma unroll
    for (int mf = 0; mf < 2; ++mf)
#pragma unroll
        for (int r = 0; r < 4; ++r) { mrun[mf][r] = -INFINITY; lrun[mf][r] = 0.0f; }

    const int nt = 2 * qt + 2;
    for (int kv = 0; kv < nt; ++kv) {
        __syncthreads();
        // stage K [64][64]
#pragma unroll
        for (int i = 0; i < 2; ++i) {
            int idx = tid + 256 * i;
            int row = idx >> 3, ch = (idx & 7) * 8;
            *(uint4*)&Klds[row][ch] =
                *(const uint4*)(Kg + base + (size_t)(kv * 64 + row) * DH + ch);
        }
        // stage V transposed: Vlds[d][t]
#pragma unroll
        for (int i = 0; i < 16; ++i) {
            int idx = tid + 256 * i;
            int tr = idx >> 6, d = idx & 63;
            Vlds[d][tr] = Vg[base + (size_t)(kv * 64 + tr) * DH + d];
        }
        __syncthreads();

        // S = Q K^T
        bf16x8 kb[4][2];
#pragma unroll
        for (int nf = 0; nf < 4; ++nf)
#pragma unroll
            for (int kf = 0; kf < 2; ++kf)
                kb[nf][kf] = *(const bf16x8*)&Klds[nf * 16 + l15][kf * 32 + 8 * lg];
        f32x4 s[2][4] = {};
#pragma unroll
        for (int mf = 0; mf < 2; ++mf)
#pragma unroll
            for (int nf = 0; nf < 4; ++nf)
#pragma unroll
                for (int kf = 0; kf < 2; ++kf)
                    s[mf][nf] = mfma_bf16(qf[mf][kf], kb[nf][kf], s[mf][nf]);

        // causal mask
        const int qrb = qt * 128 + w * 32;
#pragma unroll
        for (int mf = 0; mf < 2; ++mf)
#pragma unroll
            for (int nf = 0; nf < 4; ++nf)
#pragma unroll
                for (int r = 0; r < 4; ++r) {
                    int qg = qrb + mf * 16 + 4 * lg + r;
                    int kg = kv * 64 + nf * 16 + l15;
                    if (kg > qg) s[mf][nf][r] = -1e30f;
                }

        // online softmax
#pragma unroll
        for (int mf = 0; mf < 2; ++mf) {
#pragma unroll
            for (int r = 0; r < 4; ++r) {
                float t = fmaxf(fmaxf(s[mf][0][r], s[mf][1][r]),
                                fmaxf(s[mf][2][r], s[mf][3][r]));
#pragma unroll
                for (int off = 1; off < 16; off <<= 1) t = fmaxf(t, __shfl_xor(t, off));
                float mnew = fmaxf(mrun[mf][r], t);
                float alpha = __expf(mrun[mf][r] - mnew);
                mrun[mf][r] = mnew;
                float rs = 0.0f;
#pragma unroll
                for (int nf = 0; nf < 4; ++nf) {
                    float p = __expf(s[mf][nf][r] - mnew);
                    s[mf][nf][r] = p;
                    rs += p;
                }
#pragma unroll
                for (int off = 1; off < 16; off <<= 1) rs += __shfl_xor(rs, off);
                lrun[mf][r] = lrun[mf][r] * alpha + rs;
#pragma unroll
                for (int nf = 0; nf < 4; ++nf) o[mf][nf][r] *= alpha;
                int prow = w * 32 + mf * 16 + 4 * lg + r;
#pragma unroll
                for (int nf = 0; nf < 4; ++nf)
                    Plds[prow][nf * 16 + l15] = f2b(s[mf][nf][r]);
            }
        }

        // O += P V  (per-wave private P rows, no cross-wave sync needed)
        bf16x8 pa[2][2], vb[4][2];
#pragma unroll
        for (int mf = 0; mf < 2; ++mf)
#pragma unroll
            for (int kf = 0; kf < 2; ++kf)
                pa[mf][kf] = *(const bf16x8*)&Plds[w * 32 + mf * 16 + l15][kf * 32 + 8 * lg];
#pragma unroll
        for (int nf = 0; nf < 4; ++nf)
#pragma unroll
            for (int kf = 0; kf < 2; ++kf)
                vb[nf][kf] = *(const bf16x8*)&Vlds[nf * 16 + l15][kf * 32 + 8 * lg];
#pragma unroll
        for (int mf = 0; mf < 2; ++mf)
#pragma unroll
            for (int nf = 0; nf < 4; ++nf)
#pragma unroll
                for (int kf = 0; kf < 2; ++kf)
                    o[mf][nf] = mfma_bf16(pa[mf][kf], vb[nf][kf], o[mf][nf]);
    }

    // epilogue: O / l, scatter to [B,T, h*64+d]
    const int b = bh >> 4, hh = bh & 15;
#pragma unroll
    for (int mf = 0; mf < 2; ++mf)
#pragma unroll
        for (int nf = 0; nf < 4; ++nf)
#pragma unroll
            for (int r = 0; r < 4; ++r) {
                int tg = qt * 128 + w * 32 + mf * 16 + 4 * lg + r;
                int d = nf * 16 + l15;
                O[((size_t)b * TT + tg) * DM + hh * DH + d] = f2b(o[mf][nf][r] / lrun[mf][r]);
            }
}

extern "C" void kernel_launch(void* const* d_in, const int* in_sizes, int n_in,
                              void* d_out, int out_size, void* d_ws, size_t ws_size,
                              hipStream_t stream) {
    const float* x = (const float*)d_in[0];
    const float* wqkv = (const float*)d_in[1];
    const float* wout = (const float*)d_in[2];
    const float* ln1g = (const float*)d_in[3];
    const float* ln1b = (const float*)d_in[4];
    const float* ln2g = (const float*)d_in[5];
    const float* ln2b = (const float*)d_in[6];
    const float* w1 = (const float*)d_in[7];
    const float* b1 = (const float*)d_in[8];
    const float* w2 = (const float*)d_in[9];
    const float* b2 = (const float*)d_in[10];
    float* out = (float*)d_out;
    char* ws = (char*)d_ws;

    u16* wqkv_t = (u16*)(ws + 0);          // [3072][1024] bf16
    u16* wout_t = (u16*)(ws + 6291456);    // [1024][1024]
    u16* w1_t   = (u16*)(ws + 8388608);    // [4096][1024]
    u16* w2_t   = (u16*)(ws + 16777216);   // [1024][4096]
    u16* h_bf   = (u16*)(ws + 25165824);   // [4096][1024] (LN1, reused for LN2)
    u16* q_bf   = (u16*)(ws + 33554432);   // [B,H,T,Dh]
    u16* k_bf   = (u16*)(ws + 41943040);
    u16* v_bf   = (u16*)(ws + 50331648);
    u16* at_bf  = (u16*)(ws + 58720256);   // [4096][1024]
    float* x1   = (float*)(ws + 67108864); // [4096][1024] fp32
    u16* ff1_bf = q_bf;                    // aliases q/k/v/at (dead by FF1): [4096][4096]

    transW<<<dim3(96, 32), 256, 0, stream>>>(wqkv, wqkv_t, 1024, 3072);
    transW<<<dim3(32, 32), 256, 0, stream>>>(wout, wout_t, 1024, 1024);
    transW<<<dim3(128, 32), 256, 0, stream>>>(w1, w1_t, 1024, 4096);
    transW<<<dim3(32, 128), 256, 0, stream>>>(w2, w2_t, 4096, 1024);

    ln_kernel<<<4096, 256, 0, stream>>>(x, ln1g, ln1b, h_bf);

    gemm_kernel<0><<<dim3(24, 32), 256, 0, stream>>>(h_bf, wqkv_t, 4096, 3072, 1024,
                                                     q_bf, k_bf, v_bf,
                                                     nullptr, nullptr, nullptr, nullptr);

    attn_kernel<<<dim3(16, 32), 256, 0, stream>>>(q_bf, k_bf, v_bf, at_bf);

    gemm_kernel<1><<<dim3(8, 32), 256, 0, stream>>>(at_bf, wout_t, 4096, 1024, 1024,
                                                    nullptr, nullptr, nullptr,
                                                    x, x1, nullptr, nullptr);

    ln_kernel<<<4096, 256, 0, stream>>>(x1, ln2g, ln2b, h_bf);

    gemm_kernel<2><<<dim3(32, 32), 256, 0, stream>>>(h_bf, w1_t, 4096, 4096, 1024,
                                                     nullptr, nullptr, nullptr,
                                                     nullptr, nullptr, b1, ff1_bf);

    gemm_kernel<3><<<dim3(8, 32), 256, 0, stream>>>(ff1_bf, w2_t, 4096, 1024, 4096,
                                                    nullptr, nullptr, nullptr,
                                                    x1, out, b2, nullptr);
}

// Round 2
// 327.558 us; speedup vs baseline: 1.1509x; 1.1509x over previous
//
#include <hip/hip_runtime.h>
#include <hip/hip_bf16.h>
#include <cstdint>

#define DM 1024
#define DFF 4096
#define NB 2
#define TT 2048
#define NH 16
#define DH 64

typedef unsigned short u16;
typedef __bf16 bf16x8 __attribute__((ext_vector_type(8)));
typedef float f32x4 __attribute__((ext_vector_type(4)));
typedef unsigned short ushort8v __attribute__((ext_vector_type(8)));

__device__ __forceinline__ u16 f2b(float f) {
    union { float f; unsigned u; } v; v.f = f;
    unsigned u = v.u;
    return (u16)((u + 0x7FFFu + ((u >> 16) & 1u)) >> 16);
}

__device__ __forceinline__ f32x4 mfma_bf16(bf16x8 a, bf16x8 b, f32x4 c) {
    return __builtin_amdgcn_mfma_f32_16x16x32_bf16(a, b, c, 0, 0, 0);
}

__device__ __forceinline__ void gload_lds16(const void* g, void* l) {
    __builtin_amdgcn_global_load_lds((const __attribute__((address_space(1))) unsigned int*)g,
                                     (__attribute__((address_space(3))) unsigned int*)l, 16, 0, 0);
}

// ---------------- transpose + fp32->bf16 convert: Wt[n][k] = bf16(W[k][n]) ----------------
__global__ __launch_bounds__(256) void transW(const float* __restrict__ W, u16* __restrict__ Wt,
                                              int K, int N) {
    __shared__ float t[32][33];
    int tx = threadIdx.x & 31, ty = threadIdx.x >> 5;
    int k0 = blockIdx.y * 32, n0 = blockIdx.x * 32;
#pragma unroll
    for (int j = 0; j < 4; ++j)
        t[ty + 8 * j][tx] = W[(size_t)(k0 + ty + 8 * j) * N + n0 + tx];
    __syncthreads();
#pragma unroll
    for (int j = 0; j < 4; ++j)
        Wt[(size_t)(n0 + ty + 8 * j) * K + k0 + tx] = f2b(t[tx][ty + 8 * j]);
}

// ---------------- LayerNorm fp32 -> bf16 ----------------
__global__ __launch_bounds__(256) void ln_kernel(const float* __restrict__ X,
                                                 const float* __restrict__ g,
                                                 const float* __restrict__ bt,
                                                 u16* __restrict__ H) {
    int row = blockIdx.x, tid = threadIdx.x;
    float4 v = ((const float4*)(X + (size_t)row * DM))[tid];
    float s = v.x + v.y + v.z + v.w;
    float ss = v.x * v.x + v.y * v.y + v.z * v.z + v.w * v.w;
#pragma unroll
    for (int off = 32; off >= 1; off >>= 1) {
        s += __shfl_xor(s, off);
        ss += __shfl_xor(ss, off);
    }
    __shared__ float sb[8];
    int w = tid >> 6, lane = tid & 63;
    if (lane == 0) { sb[w] = s; sb[4 + w] = ss; }
    __syncthreads();
    s = sb[0] + sb[1] + sb[2] + sb[3];
    ss = sb[4] + sb[5] + sb[6] + sb[7];
    float mu = s * (1.0f / DM);
    float var = ss * (1.0f / DM) - mu * mu;
    float rstd = rsqrtf(var + 1e-5f);
    float4 gv = ((const float4*)g)[tid];
    float4 bv = ((const float4*)bt)[tid];
    ushort4 hv;
    hv.x = f2b((v.x - mu) * rstd * gv.x + bv.x);
    hv.y = f2b((v.y - mu) * rstd * gv.y + bv.y);
    hv.z = f2b((v.z - mu) * rstd * gv.z + bv.z);
    hv.w = f2b((v.w - mu) * rstd * gv.w + bv.w);
    ((ushort4*)(H + (size_t)row * DM))[tid] = hv;
}

// ---------------- bf16 MFMA GEMM (m97 structure: global_load_lds, linear LDS) ----------------
// MODE 0: scatter to q(scaled by 1/8*log2e)/k/v [B,H,T,Dh] bf16
// MODE 1: outf = resid + C (fp32)
// MODE 2: outbf = gelu(C + bias) bf16
// MODE 3: outf = resid + C + bias (fp32)
template <int MODE>
__global__ __launch_bounds__(256) void gemm_kernel(
    const u16* __restrict__ A, const u16* __restrict__ Bt, int M, int N, int K,
    u16* __restrict__ oq, u16* __restrict__ ok, u16* __restrict__ ov,
    const float* __restrict__ resid, float* __restrict__ outf,
    const float* __restrict__ bias, u16* __restrict__ outbf) {
    __shared__ __align__(16) u16 Alds[128][64];
    __shared__ __align__(16) u16 Blds[128][64];
    const int tid = threadIdx.x;
    const int lane = tid & 63;
    const int w = tid >> 6;
    const int wr = w >> 1, wc = w & 1;
    const int bm = blockIdx.y * 128, bn = blockIdx.x * 128;
    const int l15 = lane & 15, lg = lane >> 4;
    const int srow = tid >> 3, sch = (tid & 7) * 8;

    f32x4 acc[4][4] = {};
    const u16* Ap = A + (size_t)(bm + srow) * K + sch;
    const u16* Bp = Bt + (size_t)(bn + srow) * K + sch;

    for (int k0 = 0; k0 < K; k0 += 64) {
#pragma unroll
        for (int i = 0; i < 4; ++i) {
            gload_lds16(Ap + (size_t)(32 * i) * K + k0, &Alds[srow + 32 * i][sch]);
            gload_lds16(Bp + (size_t)(32 * i) * K + k0, &Blds[srow + 32 * i][sch]);
        }
        __syncthreads();
#pragma unroll
        for (int kk = 0; kk < 2; ++kk) {
            const int kc = kk * 32 + 8 * lg;
            bf16x8 af[4], bfr[4];
#pragma unroll
            for (int f = 0; f < 4; ++f) {
                af[f] = *(const bf16x8*)&Alds[wr * 64 + f * 16 + l15][kc];
                bfr[f] = *(const bf16x8*)&Blds[wc * 64 + f * 16 + l15][kc];
            }
#pragma unroll
            for (int mi = 0; mi < 4; ++mi)
#pragma unroll
                for (int ni = 0; ni < 4; ++ni)
                    acc[mi][ni] = mfma_bf16(af[mi], bfr[ni], acc[mi][ni]);
        }
        __syncthreads();
    }

    const int m0 = bm + wr * 64, n0 = bn + wc * 64;
#pragma unroll
    for (int mi = 0; mi < 4; ++mi) {
#pragma unroll
        for (int ni = 0; ni < 4; ++ni) {
#pragma unroll
            for (int r = 0; r < 4; ++r) {
                int m = m0 + mi * 16 + 4 * lg + r;
                int n = n0 + ni * 16 + l15;
                float v = acc[mi][ni][r];
                if constexpr (MODE == 0) {
                    int which = n >> 10, hh = (n >> 6) & 15, d = n & 63;
                    int b = m >> 11, t = m & 2047;
                    u16* dst = which == 0 ? oq : (which == 1 ? ok : ov);
                    if (which == 0) v *= 0.18033688f;  // (1/sqrt(DH)) * log2(e)
                    dst[(((size_t)(b * NH + hh)) * TT + t) * DH + d] = f2b(v);
                } else if constexpr (MODE == 1) {
                    size_t o = (size_t)m * N + n;
                    outf[o] = resid[o] + v;
                } else if constexpr (MODE == 2) {
                    float z = v + bias[n];
                    outbf[(size_t)m * N + n] =
                        f2b(0.5f * z * (1.0f + erff(z * 0.70710678118654752f)));
                } else {
                    size_t o = (size_t)m * N + n;
                    outf[o] = resid[o] + v + bias[n];
                }
            }
        }
    }
}

// ---------------- flash attention, causal, bf16 MFMA, balanced + double-buffered ----------------
// grid (16, 32) = 512 blocks, 256 threads. Block handles q-tiles p and 31-p (64 rows each):
// total KV-iters = (p+1) + (32-p) = 33 for every block. XCD swizzle: 4 heads per XCD.
__global__ __launch_bounds__(256) void attn_kernel(const u16* __restrict__ Q,
                                                   const u16* __restrict__ Kg,
                                                   const u16* __restrict__ Vg,
                                                   u16* __restrict__ O) {
    __shared__ __align__(16) u16 Klds[2][64][72];
    __shared__ __align__(16) u16 Vt[2][64][72];   // transposed: Vt[d][t]
    __shared__ __align__(16) u16 Plds[64][72];    // per-wave-private 16-row bands
    const int tid = threadIdx.x, lane = tid & 63, w = tid >> 6;
    const int l15 = lane & 15, lg = lane >> 4;

    int id = blockIdx.x + (blockIdx.y << 4);
    int sw = (id & 7) * 64 + (id >> 3);           // XCD k -> heads 4k..4k+3
    const int p = sw & 15, bh = sw >> 4;
    const size_t base = (size_t)bh * TT * DH;
    const int b = bh >> 4, hh = bh & 15;

    const int krow = tid >> 3, kch = (tid & 7) * 8;  // K staging: rows krow, krow+32
    const int vd0 = w * 8;                            // V staging: lane = t, d0 in {8w, 8w+32}

    ushort8v ka0, ka1, va0, va1;
    int kvbase = 0;

    for (int half = 0; half < 2; ++half) {
        const int qt = half ? (31 - p) : p;
        const int nkv = qt + 1;
        const int qrow = qt * 64 + w * 16 + l15;
        const bf16x8 qf0 = *(const bf16x8*)(Q + base + (size_t)qrow * DH + 8 * lg);
        const bf16x8 qf1 = *(const bf16x8*)(Q + base + (size_t)qrow * DH + 32 + 8 * lg);

        f32x4 o[4] = {};
        float mrun[4] = {-INFINITY, -INFINITY, -INFINITY, -INFINITY};
        float lsum[4] = {0.0f, 0.0f, 0.0f, 0.0f};

        // ---- prologue: tile 0 -> buf 0; issue tile 1 loads ----
        {
            const u16* kp = Kg + base + (size_t)krow * DH + kch;
            ka0 = *(const ushort8v*)kp;
            ka1 = *(const ushort8v*)(kp + 32 * DH);
            const u16* vp = Vg + base + (size_t)lane * DH + vd0;
            va0 = *(const ushort8v*)vp;
            va1 = *(const ushort8v*)(vp + 32);
            *(ushort8v*)&Klds[0][krow][kch] = ka0;
            *(ushort8v*)&Klds[0][krow + 32][kch] = ka1;
#pragma unroll
            for (int j = 0; j < 8; ++j) {
                Vt[0][vd0 + j][lane] = va0[j];
                Vt[0][vd0 + 32 + j][lane] = va1[j];
            }
            if (nkv > 1) {
                const u16* kp1 = Kg + base + (size_t)(64 + krow) * DH + kch;
                ka0 = *(const ushort8v*)kp1;
                ka1 = *(const ushort8v*)(kp1 + 32 * DH);
                const u16* vp1 = Vg + base + (size_t)(64 + lane) * DH + vd0;
                va0 = *(const ushort8v*)vp1;
                va1 = *(const ushort8v*)(vp1 + 32);
            }
        }
        __syncthreads();

        int cur = 0;
        for (int kv = 0; kv < nkv; ++kv) {
            // ---- S = Q K^T ----
            bf16x8 kb[4][2];
#pragma unroll
            for (int nf = 0; nf < 4; ++nf) {
                kb[nf][0] = *(const bf16x8*)&Klds[cur][nf * 16 + l15][8 * lg];
                kb[nf][1] = *(const bf16x8*)&Klds[cur][nf * 16 + l15][32 + 8 * lg];
            }
            f32x4 s[4] = {};
#pragma unroll
            for (int nf = 0; nf < 4; ++nf) {
                s[nf] = mfma_bf16(qf0, kb[nf][0], s[nf]);
                s[nf] = mfma_bf16(qf1, kb[nf][1], s[nf]);
            }

            // ---- causal mask (diagonal tile only) ----
            if (kv == qt) {
                const int qr = qt * 64 + w * 16 + 4 * lg;
#pragma unroll
                for (int nf = 0; nf < 4; ++nf) {
                    const int kg = kv * 64 + nf * 16 + l15;
#pragma unroll
                    for (int r = 0; r < 4; ++r)
                        if (kg > qr + r) s[nf][r] = -1e30f;
                }
            }

            // ---- online softmax (base-2; log2e folded into Q scale) ----
#pragma unroll
            for (int r = 0; r < 4; ++r) {
                float t = fmaxf(fmaxf(s[0][r], s[1][r]), fmaxf(s[2][r], s[3][r]));
                t = fmaxf(t, __shfl_xor(t, 1));
                t = fmaxf(t, __shfl_xor(t, 2));
                t = fmaxf(t, __shfl_xor(t, 4));
                t = fmaxf(t, __shfl_xor(t, 8));
                const float mnew = fmaxf(mrun[r], t);
                const float alpha = exp2f(mrun[r] - mnew);
                mrun[r] = mnew;
                float ps = 0.0f;
#pragma unroll
                for (int nf = 0; nf < 4; ++nf) {
                    const float pp = exp2f(s[nf][r] - mnew);
                    s[nf][r] = pp;
                    ps += pp;
                }
                lsum[r] = lsum[r] * alpha + ps;   // per-lane partial; reduced at end
#pragma unroll
                for (int nf = 0; nf < 4; ++nf) o[nf][r] *= alpha;
                const int prow = w * 16 + 4 * lg + r;
#pragma unroll
                for (int nf = 0; nf < 4; ++nf)
                    Plds[prow][nf * 16 + l15] = f2b(s[nf][r]);
            }

            // ---- stage next tile into buf^1; issue loads for kv+2 ----
            if (kv + 1 < nkv) {
                *(ushort8v*)&Klds[cur ^ 1][krow][kch] = ka0;
                *(ushort8v*)&Klds[cur ^ 1][krow + 32][kch] = ka1;
#pragma unroll
                for (int j = 0; j < 8; ++j) {
                    Vt[cur ^ 1][vd0 + j][lane] = va0[j];
                    Vt[cur ^ 1][vd0 + 32 + j][lane] = va1[j];
                }
                if (kv + 2 < nkv) {
                    const u16* kp = Kg + base + (size_t)((kv + 2) * 64 + krow) * DH + kch;
                    ka0 = *(const ushort8v*)kp;
                    ka1 = *(const ushort8v*)(kp + 32 * DH);
                    const u16* vp = Vg + base + (size_t)((kv + 2) * 64 + lane) * DH + vd0;
                    va0 = *(const ushort8v*)vp;
                    va1 = *(const ushort8v*)(vp + 32);
                }
            }

            // ---- O += P V ----
            bf16x8 pa0 = *(const bf16x8*)&Plds[w * 16 + l15][8 * lg];
            bf16x8 pa1 = *(const bf16x8*)&Plds[w * 16 + l15][32 + 8 * lg];
#pragma unroll
            for (int nf = 0; nf < 4; ++nf) {
                bf16x8 vb0 = *(const bf16x8*)&Vt[cur][nf * 16 + l15][8 * lg];
                bf16x8 vb1 = *(const bf16x8*)&Vt[cur][nf * 16 + l15][32 + 8 * lg];
                o[nf] = mfma_bf16(pa0, vb0, o[nf]);
                o[nf] = mfma_bf16(pa1, vb1, o[nf]);
            }

            __syncthreads();
            cur ^= 1;
        }

        // ---- epilogue: O / l, scatter to [B,T, h*64+d] ----
#pragma unroll
        for (int r = 0; r < 4; ++r) {
            float l = lsum[r];
            l += __shfl_xor(l, 1);
            l += __shfl_xor(l, 2);
            l += __shfl_xor(l, 4);
            l += __shfl_xor(l, 8);
            lsum[r] = 1.0f / l;
        }
        const int tgb = qt * 64 + w * 16 + 4 * lg;
#pragma unroll
        for (int nf = 0; nf < 4; ++nf)
#pragma unroll
            for (int r = 0; r < 4; ++r)
                O[((size_t)b * TT + tgb + r) * DM + hh * DH + nf * 16 + l15] =
                    f2b(o[nf][r] * lsum[r]);
    }
}

extern "C" void kernel_launch(void* const* d_in, const int* in_sizes, int n_in,
                              void* d_out, int out_size, void* d_ws, size_t ws_size,
                              hipStream_t stream) {
    const float* x = (const float*)d_in[0];
    const float* wqkv = (const float*)d_in[1];
    const float* wout = (const float*)d_in[2];
    const float* ln1g = (const float*)d_in[3];
    const float* ln1b = (const float*)d_in[4];
    const float* ln2g = (const float*)d_in[5];
    const float* ln2b = (const float*)d_in[6];
    const float* w1 = (const float*)d_in[7];
    const float* b1 = (const float*)d_in[8];
    const float* w2 = (const float*)d_in[9];
    const float* b2 = (const float*)d_in[10];
    float* out = (float*)d_out;
    char* ws = (char*)d_ws;

    u16* wqkv_t = (u16*)(ws + 0);          // [3072][1024] bf16
    u16* wout_t = (u16*)(ws + 6291456);    // [1024][1024]
    u16* w1_t   = (u16*)(ws + 8388608);    // [4096][1024]
    u16* w2_t   = (u16*)(ws + 16777216);   // [1024][4096]
    u16* h_bf   = (u16*)(ws + 25165824);   // [4096][1024] (LN1, reused for LN2)
    u16* q_bf   = (u16*)(ws + 33554432);   // [B,H,T,Dh]
    u16* k_bf   = (u16*)(ws + 41943040);
    u16* v_bf   = (u16*)(ws + 50331648);
    u16* at_bf  = (u16*)(ws + 58720256);   // [4096][1024]
    float* x1   = (float*)(ws + 67108864); // [4096][1024] fp32
    u16* ff1_bf = q_bf;                    // aliases q/k/v/at (dead by FF1): [4096][4096]

    transW<<<dim3(96, 32), 256, 0, stream>>>(wqkv, wqkv_t, 1024, 3072);
    transW<<<dim3(32, 32), 256, 0, stream>>>(wout, wout_t, 1024, 1024);
    transW<<<dim3(128, 32), 256, 0, stream>>>(w1, w1_t, 1024, 4096);
    transW<<<dim3(32, 128), 256, 0, stream>>>(w2, w2_t, 4096, 1024);

    ln_kernel<<<4096, 256, 0, stream>>>(x, ln1g, ln1b, h_bf);

    gemm_kernel<0><<<dim3(24, 32), 256, 0, stream>>>(h_bf, wqkv_t, 4096, 3072, 1024,
                                                     q_bf, k_bf, v_bf,
                                                     nullptr, nullptr, nullptr, nullptr);

    attn_kernel<<<dim3(16, 32), 256, 0, stream>>>(q_bf, k_bf, v_bf, at_bf);

    gemm_kernel<1><<<dim3(8, 32), 256, 0, stream>>>(at_bf, wout_t, 4096, 1024, 1024,
                                                    nullptr, nullptr, nullptr,
                                                    x, x1, nullptr, nullptr);

    ln_kernel<<<4096, 256, 0, stream>>>(x1, ln2g, ln2b, h_bf);

    gemm_kernel<2><<<dim3(32, 32), 256, 0, stream>>>(h_bf, w1_t, 4096, 4096, 1024,
                                                     nullptr, nullptr, nullptr,
                                                     nullptr, nullptr, b1, ff1_bf);

    gemm_kernel<3><<<dim3(8, 32), 256, 0, stream>>>(ff1_bf, w2_t, 4096, 1024, 4096,
                                                    nullptr, nullptr, nullptr,
                                                    x1, out, b2, nullptr);
}

// Round 3
// 279.964 us; speedup vs baseline: 1.3466x; 1.1700x over previous
//
#include <hip/hip_runtime.h>
#include <hip/hip_bf16.h>
#include <cstdint>

#define DM 1024
#define DFF 4096
#define NB 2
#define TT 2048
#define NH 16
#define DH 64

typedef unsigned short u16;
typedef __bf16 bf16x8 __attribute__((ext_vector_type(8)));
typedef float f32x4 __attribute__((ext_vector_type(4)));
typedef unsigned short ushort8v __attribute__((ext_vector_type(8)));

__device__ __forceinline__ u16 f2b(float f) {
    union { float f; unsigned u; } v; v.f = f;
    unsigned u = v.u;
    return (u16)((u + 0x7FFFu + ((u >> 16) & 1u)) >> 16);
}

__device__ __forceinline__ f32x4 mfma_bf16(bf16x8 a, bf16x8 b, f32x4 c) {
    return __builtin_amdgcn_mfma_f32_16x16x32_bf16(a, b, c, 0, 0, 0);
}

__device__ __forceinline__ void gload_lds16(const void* g, void* l) {
    __builtin_amdgcn_global_load_lds((const __attribute__((address_space(1))) unsigned int*)g,
                                     (__attribute__((address_space(3))) unsigned int*)l, 16, 0, 0);
}

// ---------------- transpose + fp32->bf16 convert: Wt[n][k] = bf16(W[k][n]) ----------------
__global__ __launch_bounds__(256) void transW(const float* __restrict__ W, u16* __restrict__ Wt,
                                              int K, int N) {
    __shared__ float t[32][33];
    int tx = threadIdx.x & 31, ty = threadIdx.x >> 5;
    int k0 = blockIdx.y * 32, n0 = blockIdx.x * 32;
#pragma unroll
    for (int j = 0; j < 4; ++j)
        t[ty + 8 * j][tx] = W[(size_t)(k0 + ty + 8 * j) * N + n0 + tx];
    __syncthreads();
#pragma unroll
    for (int j = 0; j < 4; ++j)
        Wt[(size_t)(n0 + ty + 8 * j) * K + k0 + tx] = f2b(t[tx][ty + 8 * j]);
}

// ---------------- LayerNorm fp32 -> bf16 ----------------
__global__ __launch_bounds__(256) void ln_kernel(const float* __restrict__ X,
                                                 const float* __restrict__ g,
                                                 const float* __restrict__ bt,
                                                 u16* __restrict__ H) {
    int row = blockIdx.x, tid = threadIdx.x;
    float4 v = ((const float4*)(X + (size_t)row * DM))[tid];
    float s = v.x + v.y + v.z + v.w;
    float ss = v.x * v.x + v.y * v.y + v.z * v.z + v.w * v.w;
#pragma unroll
    for (int off = 32; off >= 1; off >>= 1) {
        s += __shfl_xor(s, off);
        ss += __shfl_xor(ss, off);
    }
    __shared__ float sb[8];
    int w = tid >> 6, lane = tid & 63;
    if (lane == 0) { sb[w] = s; sb[4 + w] = ss; }
    __syncthreads();
    s = sb[0] + sb[1] + sb[2] + sb[3];
    ss = sb[4] + sb[5] + sb[6] + sb[7];
    float mu = s * (1.0f / DM);
    float var = ss * (1.0f / DM) - mu * mu;
    float rstd = rsqrtf(var + 1e-5f);
    float4 gv = ((const float4*)g)[tid];
    float4 bv = ((const float4*)bt)[tid];
    ushort4 hv;
    hv.x = f2b((v.x - mu) * rstd * gv.x + bv.x);
    hv.y = f2b((v.y - mu) * rstd * gv.y + bv.y);
    hv.z = f2b((v.z - mu) * rstd * gv.z + bv.z);
    hv.w = f2b((v.w - mu) * rstd * gv.w + bv.w);
    ((ushort4*)(H + (size_t)row * DM))[tid] = hv;
}

// ---------------- bf16 MFMA GEMM ----------------
// T2 swizzle: element (row, chunk) stored at physical chunk^(row&7) (16B chunks, 128B rows).
// Staged via global_load_lds with pre-swizzled global SOURCE + linear LDS dest (m201 pattern).
// DBUF=1: double-buffered, counted vmcnt(8), raw barriers (for 1-block/CU grids).
// MODE 0: scatter to q(scaled by 1/8*log2e)/k/v ; 1: resid+C fp32 ; 2: gelu(C+bias) bf16 ; 3: resid+C+bias fp32
template <int MODE, int DBUF>
__global__ __launch_bounds__(256) void gemm_kernel(
    const u16* __restrict__ A, const u16* __restrict__ Bt, int M, int N, int K,
    u16* __restrict__ oq, u16* __restrict__ ok, u16* __restrict__ ov,
    const float* __restrict__ resid, float* __restrict__ outf,
    const float* __restrict__ bias, u16* __restrict__ outbf) {
    __shared__ __align__(16) u16 Alds[DBUF + 1][128][64];
    __shared__ __align__(16) u16 Blds[DBUF + 1][128][64];
    const int tid = threadIdx.x;
    const int lane = tid & 63;
    const int w = tid >> 6;
    const int wr = w >> 1, wc = w & 1;
    // T1: bijective chunked XCD swizzle (all grids divisible by 8)
    int bid = blockIdx.x + gridDim.x * blockIdx.y;
    const int nwg = gridDim.x * gridDim.y;
    bid = (bid & 7) * (nwg >> 3) + (bid >> 3);
    const int bm = (bid / gridDim.x) * 128, bn = (bid % gridDim.x) * 128;
    const int l15 = lane & 15, lg = lane >> 4;
    const int srow = tid >> 3, pch = tid & 7;
    const int lc = pch ^ (srow & 7);  // logical source chunk for this thread's linear dest

    f32x4 acc[4][4] = {};
    const u16* Ap = A + (size_t)(bm + srow) * K + lc * 8;
    const u16* Bp = Bt + (size_t)(bn + srow) * K + lc * 8;

#define STAGE(buf, k0)                                                          \
    {                                                                           \
        _Pragma("unroll") for (int i = 0; i < 4; ++i) {                         \
            gload_lds16(Ap + (size_t)(32 * i) * K + (k0), &Alds[buf][srow + 32 * i][pch * 8]); \
            gload_lds16(Bp + (size_t)(32 * i) * K + (k0), &Blds[buf][srow + 32 * i][pch * 8]); \
        }                                                                       \
    }

#define COMPUTE(buf)                                                            \
    {                                                                           \
        _Pragma("unroll") for (int kk = 0; kk < 2; ++kk) {                      \
            bf16x8 af[4], bfr[4];                                               \
            _Pragma("unroll") for (int f = 0; f < 4; ++f) {                     \
                const int ar = wr * 64 + f * 16 + l15;                          \
                const int br = wc * 64 + f * 16 + l15;                          \
                const int kch = kk * 4 + lg;                                    \
                af[f] = *(const bf16x8*)&Alds[buf][ar][(kch ^ (ar & 7)) * 8];   \
                bfr[f] = *(const bf16x8*)&Blds[buf][br][(kch ^ (br & 7)) * 8];  \
            }                                                                   \
            _Pragma("unroll") for (int mi = 0; mi < 4; ++mi)                    \
                _Pragma("unroll") for (int ni = 0; ni < 4; ++ni)                \
                    acc[mi][ni] = mfma_bf16(af[mi], bfr[ni], acc[mi][ni]);      \
        }                                                                       \
    }

    if constexpr (DBUF == 0) {
        for (int k0 = 0; k0 < K; k0 += 64) {
            STAGE(0, k0);
            __syncthreads();
            COMPUTE(0);
            __syncthreads();
        }
    } else {
        STAGE(0, 0);
        for (int k0 = 0; k0 < K; k0 += 64) {
            const int cur = (k0 >> 6) & 1;
            if (k0 + 64 < K) {
                STAGE(cur ^ 1, k0 + 64);
                asm volatile("s_waitcnt vmcnt(8)" ::: "memory");
            } else {
                asm volatile("s_waitcnt vmcnt(0)" ::: "memory");
            }
            __builtin_amdgcn_sched_barrier(0);
            __builtin_amdgcn_s_barrier();
            __builtin_amdgcn_sched_barrier(0);
            COMPUTE(cur);
            __builtin_amdgcn_s_barrier();
        }
    }
#undef STAGE
#undef COMPUTE

    const int m0 = bm + wr * 64, n0 = bn + wc * 64;
#pragma unroll
    for (int mi = 0; mi < 4; ++mi) {
#pragma unroll
        for (int ni = 0; ni < 4; ++ni) {
#pragma unroll
            for (int r = 0; r < 4; ++r) {
                int m = m0 + mi * 16 + 4 * lg + r;
                int n = n0 + ni * 16 + l15;
                float v = acc[mi][ni][r];
                if constexpr (MODE == 0) {
                    int which = n >> 10, hh = (n >> 6) & 15, d = n & 63;
                    int b = m >> 11, t = m & 2047;
                    u16* dst = which == 0 ? oq : (which == 1 ? ok : ov);
                    if (which == 0) v *= 0.18033688f;  // (1/sqrt(DH)) * log2(e)
                    dst[(((size_t)(b * NH + hh)) * TT + t) * DH + d] = f2b(v);
                } else if constexpr (MODE == 1) {
                    size_t o = (size_t)m * N + n;
                    outf[o] = resid[o] + v;
                } else if constexpr (MODE == 2) {
                    float z = v + bias[n];
                    outbf[(size_t)m * N + n] =
                        f2b(0.5f * z * (1.0f + erff(z * 0.70710678118654752f)));
                } else {
                    size_t o = (size_t)m * N + n;
                    outf[o] = resid[o] + v + bias[n];
                }
            }
        }
    }
}

// ---------------- flash attention, causal, bf16 MFMA, balanced + double-buffered ----------------
__global__ __launch_bounds__(256) void attn_kernel(const u16* __restrict__ Q,
                                                   const u16* __restrict__ Kg,
                                                   const u16* __restrict__ Vg,
                                                   u16* __restrict__ O) {
    __shared__ __align__(16) u16 Klds[2][64][72];
    __shared__ __align__(16) u16 Vt[2][64][72];   // transposed: Vt[d][t]
    __shared__ __align__(16) u16 Plds[64][72];    // per-wave-private 16-row bands
    const int tid = threadIdx.x, lane = tid & 63, w = tid >> 6;
    const int l15 = lane & 15, lg = lane >> 4;

    int id = blockIdx.x + (blockIdx.y << 4);
    int sw = (id & 7) * 64 + (id >> 3);           // XCD k -> heads 4k..4k+3
    const int p = sw & 15, bh = sw >> 4;
    const size_t base = (size_t)bh * TT * DH;
    const int b = bh >> 4, hh = bh & 15;

    const int krow = tid >> 3, kch = (tid & 7) * 8;
    const int vd0 = w * 8;

    ushort8v ka0, ka1, va0, va1;

    for (int half = 0; half < 2; ++half) {
        const int qt = half ? (31 - p) : p;
        const int nkv = qt + 1;
        const int qrow = qt * 64 + w * 16 + l15;
        const bf16x8 qf0 = *(const bf16x8*)(Q + base + (size_t)qrow * DH + 8 * lg);
        const bf16x8 qf1 = *(const bf16x8*)(Q + base + (size_t)qrow * DH + 32 + 8 * lg);

        f32x4 o[4] = {};
        float mrun[4] = {-INFINITY, -INFINITY, -INFINITY, -INFINITY};
        float lsum[4] = {0.0f, 0.0f, 0.0f, 0.0f};

        {
            const u16* kp = Kg + base + (size_t)krow * DH + kch;
            ka0 = *(const ushort8v*)kp;
            ka1 = *(const ushort8v*)(kp + 32 * DH);
            const u16* vp = Vg + base + (size_t)lane * DH + vd0;
            va0 = *(const ushort8v*)vp;
            va1 = *(const ushort8v*)(vp + 32);
            *(ushort8v*)&Klds[0][krow][kch] = ka0;
            *(ushort8v*)&Klds[0][krow + 32][kch] = ka1;
#pragma unroll
            for (int j = 0; j < 8; ++j) {
                Vt[0][vd0 + j][lane] = va0[j];
                Vt[0][vd0 + 32 + j][lane] = va1[j];
            }
            if (nkv > 1) {
                const u16* kp1 = Kg + base + (size_t)(64 + krow) * DH + kch;
                ka0 = *(const ushort8v*)kp1;
                ka1 = *(const ushort8v*)(kp1 + 32 * DH);
                const u16* vp1 = Vg + base + (size_t)(64 + lane) * DH + vd0;
                va0 = *(const ushort8v*)vp1;
                va1 = *(const ushort8v*)(vp1 + 32);
            }
        }
        __syncthreads();

        int cur = 0;
        for (int kv = 0; kv < nkv; ++kv) {
            bf16x8 kb[4][2];
#pragma unroll
            for (int nf = 0; nf < 4; ++nf) {
                kb[nf][0] = *(const bf16x8*)&Klds[cur][nf * 16 + l15][8 * lg];
                kb[nf][1] = *(const bf16x8*)&Klds[cur][nf * 16 + l15][32 + 8 * lg];
            }
            f32x4 s[4] = {};
#pragma unroll
            for (int nf = 0; nf < 4; ++nf) {
                s[nf] = mfma_bf16(qf0, kb[nf][0], s[nf]);
                s[nf] = mfma_bf16(qf1, kb[nf][1], s[nf]);
            }

            if (kv == qt) {
                const int qr = qt * 64 + w * 16 + 4 * lg;
#pragma unroll
                for (int nf = 0; nf < 4; ++nf) {
                    const int kg = kv * 64 + nf * 16 + l15;
#pragma unroll
                    for (int r = 0; r < 4; ++r)
                        if (kg > qr + r) s[nf][r] = -1e30f;
                }
            }

#pragma unroll
            for (int r = 0; r < 4; ++r) {
                float t = fmaxf(fmaxf(s[0][r], s[1][r]), fmaxf(s[2][r], s[3][r]));
                t = fmaxf(t, __shfl_xor(t, 1));
                t = fmaxf(t, __shfl_xor(t, 2));
                t = fmaxf(t, __shfl_xor(t, 4));
                t = fmaxf(t, __shfl_xor(t, 8));
                const float mnew = fmaxf(mrun[r], t);
                const float alpha = exp2f(mrun[r] - mnew);
                mrun[r] = mnew;
                float ps = 0.0f;
#pragma unroll
                for (int nf = 0; nf < 4; ++nf) {
                    const float pp = exp2f(s[nf][r] - mnew);
                    s[nf][r] = pp;
                    ps += pp;
                }
                lsum[r] = lsum[r] * alpha + ps;
#pragma unroll
                for (int nf = 0; nf < 4; ++nf) o[nf][r] *= alpha;
                const int prow = w * 16 + 4 * lg + r;
#pragma unroll
                for (int nf = 0; nf < 4; ++nf)
                    Plds[prow][nf * 16 + l15] = f2b(s[nf][r]);
            }

            if (kv + 1 < nkv) {
                *(ushort8v*)&Klds[cur ^ 1][krow][kch] = ka0;
                *(ushort8v*)&Klds[cur ^ 1][krow + 32][kch] = ka1;
#pragma unroll
                for (int j = 0; j < 8; ++j) {
                    Vt[cur ^ 1][vd0 + j][lane] = va0[j];
                    Vt[cur ^ 1][vd0 + 32 + j][lane] = va1[j];
                }
                if (kv + 2 < nkv) {
                    const u16* kp = Kg + base + (size_t)((kv + 2) * 64 + krow) * DH + kch;
                    ka0 = *(const ushort8v*)kp;
                    ka1 = *(const ushort8v*)(kp + 32 * DH);
                    const u16* vp = Vg + base + (size_t)((kv + 2) * 64 + lane) * DH + vd0;
                    va0 = *(const ushort8v*)vp;
                    va1 = *(const ushort8v*)(vp + 32);
                }
            }

            bf16x8 pa0 = *(const bf16x8*)&Plds[w * 16 + l15][8 * lg];
            bf16x8 pa1 = *(const bf16x8*)&Plds[w * 16 + l15][32 + 8 * lg];
#pragma unroll
            for (int nf = 0; nf < 4; ++nf) {
                bf16x8 vb0 = *(const bf16x8*)&Vt[cur][nf * 16 + l15][8 * lg];
                bf16x8 vb1 = *(const bf16x8*)&Vt[cur][nf * 16 + l15][32 + 8 * lg];
                o[nf] = mfma_bf16(pa0, vb0, o[nf]);
                o[nf] = mfma_bf16(pa1, vb1, o[nf]);
            }

            __syncthreads();
            cur ^= 1;
        }

#pragma unroll
        for (int r = 0; r < 4; ++r) {
            float l = lsum[r];
            l += __shfl_xor(l, 1);
            l += __shfl_xor(l, 2);
            l += __shfl_xor(l, 4);
            l += __shfl_xor(l, 8);
            lsum[r] = 1.0f / l;
        }
        const int tgb = qt * 64 + w * 16 + 4 * lg;
#pragma unroll
        for (int nf = 0; nf < 4; ++nf)
#pragma unroll
            for (int r = 0; r < 4; ++r)
                O[((size_t)b * TT + tgb + r) * DM + hh * DH + nf * 16 + l15] =
                    f2b(o[nf][r] * lsum[r]);
    }
}

extern "C" void kernel_launch(void* const* d_in, const int* in_sizes, int n_in,
                              void* d_out, int out_size, void* d_ws, size_t ws_size,
                              hipStream_t stream) {
    const float* x = (const float*)d_in[0];
    const float* wqkv = (const float*)d_in[1];
    const float* wout = (const float*)d_in[2];
    const float* ln1g = (const float*)d_in[3];
    const float* ln1b = (const float*)d_in[4];
    const float* ln2g = (const float*)d_in[5];
    const float* ln2b = (const float*)d_in[6];
    const float* w1 = (const float*)d_in[7];
    const float* b1 = (const float*)d_in[8];
    const float* w2 = (const float*)d_in[9];
    const float* b2 = (const float*)d_in[10];
    float* out = (float*)d_out;
    char* ws = (char*)d_ws;

    u16* wqkv_t = (u16*)(ws + 0);          // [3072][1024] bf16
    u16* wout_t = (u16*)(ws + 6291456);    // [1024][1024]
    u16* w1_t   = (u16*)(ws + 8388608);    // [4096][1024]
    u16* w2_t   = (u16*)(ws + 16777216);   // [1024][4096]
    u16* h_bf   = (u16*)(ws + 25165824);   // [4096][1024] (LN1, reused for LN2)
    u16* q_bf   = (u16*)(ws + 33554432);   // [B,H,T,Dh]
    u16* k_bf   = (u16*)(ws + 41943040);
    u16* v_bf   = (u16*)(ws + 50331648);
    u16* at_bf  = (u16*)(ws + 58720256);   // [4096][1024]
    float* x1   = (float*)(ws + 67108864); // [4096][1024] fp32
    u16* ff1_bf = q_bf;                    // aliases q/k/v/at (dead by FF1): [4096][4096]

    transW<<<dim3(96, 32), 256, 0, stream>>>(wqkv, wqkv_t, 1024, 3072);
    transW<<<dim3(32, 32), 256, 0, stream>>>(wout, wout_t, 1024, 1024);
    transW<<<dim3(128, 32), 256, 0, stream>>>(w1, w1_t, 1024, 4096);
    transW<<<dim3(32, 128), 256, 0, stream>>>(w2, w2_t, 4096, 1024);

    ln_kernel<<<4096, 256, 0, stream>>>(x, ln1g, ln1b, h_bf);

    gemm_kernel<0, 0><<<dim3(24, 32), 256, 0, stream>>>(h_bf, wqkv_t, 4096, 3072, 1024,
                                                        q_bf, k_bf, v_bf,
                                                        nullptr, nullptr, nullptr, nullptr);

    attn_kernel<<<dim3(16, 32), 256, 0, stream>>>(q_bf, k_bf, v_bf, at_bf);

    gemm_kernel<1, 1><<<dim3(8, 32), 256, 0, stream>>>(at_bf, wout_t, 4096, 1024, 1024,
                                                       nullptr, nullptr, nullptr,
                                                       x, x1, nullptr, nullptr);

    ln_kernel<<<4096, 256, 0, stream>>>(x1, ln2g, ln2b, h_bf);

    gemm_kernel<2, 0><<<dim3(32, 32), 256, 0, stream>>>(h_bf, w1_t, 4096, 4096, 1024,
                                                        nullptr, nullptr, nullptr,
                                                        nullptr, nullptr, b1, ff1_bf);

    gemm_kernel<3, 1><<<dim3(8, 32), 256, 0, stream>>>(ff1_bf, w2_t, 4096, 1024, 4096,
                                                       nullptr, nullptr, nullptr,
                                                       x1, out, b2, nullptr);
}

// Round 4
// 270.266 us; speedup vs baseline: 1.3949x; 1.0359x over previous
//
#include <hip/hip_runtime.h>
#include <hip/hip_bf16.h>
#include <cstdint>

#define DM 1024
#define DFF 4096
#define NB 2
#define TT 2048
#define NH 16
#define DH 64

typedef unsigned short u16;
typedef __bf16 bf16x8 __attribute__((ext_vector_type(8)));
typedef float f32x4 __attribute__((ext_vector_type(4)));

__device__ __forceinline__ u16 f2b(float f) {
    union { float f; unsigned u; } v; v.f = f;
    unsigned u = v.u;
    return (u16)((u + 0x7FFFu + ((u >> 16) & 1u)) >> 16);
}

__device__ __forceinline__ unsigned cvtpk(float a, float b) {
    unsigned r;
    asm("v_cvt_pk_bf16_f32 %0, %1, %2" : "=v"(r) : "v"(a), "v"(b));
    return r;
}

__device__ __forceinline__ f32x4 mfma_bf16(bf16x8 a, bf16x8 b, f32x4 c) {
    return __builtin_amdgcn_mfma_f32_16x16x32_bf16(a, b, c, 0, 0, 0);
}

__device__ __forceinline__ void gload_lds16(const void* g, void* l) {
    __builtin_amdgcn_global_load_lds((const __attribute__((address_space(1))) unsigned int*)g,
                                     (__attribute__((address_space(3))) unsigned int*)l, 16, 0, 0);
}

// ---------------- transpose + fp32->bf16 convert: Wt[n][k] = bf16(W[k][n]) ----------------
__global__ __launch_bounds__(256) void transW(const float* __restrict__ W, u16* __restrict__ Wt,
                                              int K, int N) {
    __shared__ float t[32][33];
    int tx = threadIdx.x & 31, ty = threadIdx.x >> 5;
    int k0 = blockIdx.y * 32, n0 = blockIdx.x * 32;
#pragma unroll
    for (int j = 0; j < 4; ++j)
        t[ty + 8 * j][tx] = W[(size_t)(k0 + ty + 8 * j) * N + n0 + tx];
    __syncthreads();
#pragma unroll
    for (int j = 0; j < 4; ++j)
        Wt[(size_t)(n0 + ty + 8 * j) * K + k0 + tx] = f2b(t[tx][ty + 8 * j]);
}

// ---------------- LayerNorm fp32 -> bf16 ----------------
__global__ __launch_bounds__(256) void ln_kernel(const float* __restrict__ X,
                                                 const float* __restrict__ g,
                                                 const float* __restrict__ bt,
                                                 u16* __restrict__ H) {
    int row = blockIdx.x, tid = threadIdx.x;
    float4 v = ((const float4*)(X + (size_t)row * DM))[tid];
    float s = v.x + v.y + v.z + v.w;
    float ss = v.x * v.x + v.y * v.y + v.z * v.z + v.w * v.w;
#pragma unroll
    for (int off = 32; off >= 1; off >>= 1) {
        s += __shfl_xor(s, off);
        ss += __shfl_xor(ss, off);
    }
    __shared__ float sb[8];
    int w = tid >> 6, lane = tid & 63;
    if (lane == 0) { sb[w] = s; sb[4 + w] = ss; }
    __syncthreads();
    s = sb[0] + sb[1] + sb[2] + sb[3];
    ss = sb[4] + sb[5] + sb[6] + sb[7];
    float mu = s * (1.0f / DM);
    float var = ss * (1.0f / DM) - mu * mu;
    float rstd = rsqrtf(var + 1e-5f);
    float4 gv = ((const float4*)g)[tid];
    float4 bv = ((const float4*)bt)[tid];
    ushort4 hv;
    hv.x = f2b((v.x - mu) * rstd * gv.x + bv.x);
    hv.y = f2b((v.y - mu) * rstd * gv.y + bv.y);
    hv.z = f2b((v.z - mu) * rstd * gv.z + bv.z);
    hv.w = f2b((v.w - mu) * rstd * gv.w + bv.w);
    ((ushort4*)(H + (size_t)row * DM))[tid] = hv;
}

// ---------------- bf16 MFMA GEMM ----------------
// T2 swizzle: element (row, chunk) stored at physical chunk^(row&7) (16B chunks, 128B rows).
// DBUF=1: double-buffered, counted vmcnt(8), raw barriers (for 1-block/CU grids).
// MODE 0: q(scaled)/k -> [B,H,T,Dh]; v -> V^T [B,H,Dh,T] packed. 1: resid+C fp32.
// 2: gelu(C+bias) bf16. 3: resid+C+bias fp32.
template <int MODE, int DBUF>
__global__ __launch_bounds__(256) void gemm_kernel(
    const u16* __restrict__ A, const u16* __restrict__ Bt, int M, int N, int K,
    u16* __restrict__ oq, u16* __restrict__ ok, u16* __restrict__ vt,
    const float* __restrict__ resid, float* __restrict__ outf,
    const float* __restrict__ bias, u16* __restrict__ outbf) {
    __shared__ __align__(16) u16 Alds[DBUF + 1][128][64];
    __shared__ __align__(16) u16 Blds[DBUF + 1][128][64];
    const int tid = threadIdx.x;
    const int lane = tid & 63;
    const int w = tid >> 6;
    const int wr = w >> 1, wc = w & 1;
    int bid = blockIdx.x + gridDim.x * blockIdx.y;
    const int nwg = gridDim.x * gridDim.y;
    bid = (bid & 7) * (nwg >> 3) + (bid >> 3);
    const int bm = (bid / gridDim.x) * 128, bn = (bid % gridDim.x) * 128;
    const int l15 = lane & 15, lg = lane >> 4;
    const int srow = tid >> 3, pch = tid & 7;
    const int lc = pch ^ (srow & 7);

    f32x4 acc[4][4] = {};
    const u16* Ap = A + (size_t)(bm + srow) * K + lc * 8;
    const u16* Bp = Bt + (size_t)(bn + srow) * K + lc * 8;

#define STAGE(buf, k0)                                                          \
    {                                                                           \
        _Pragma("unroll") for (int i = 0; i < 4; ++i) {                         \
            gload_lds16(Ap + (size_t)(32 * i) * K + (k0), &Alds[buf][srow + 32 * i][pch * 8]); \
            gload_lds16(Bp + (size_t)(32 * i) * K + (k0), &Blds[buf][srow + 32 * i][pch * 8]); \
        }                                                                       \
    }

#define COMPUTE(buf)                                                            \
    {                                                                           \
        _Pragma("unroll") for (int kk = 0; kk < 2; ++kk) {                      \
            bf16x8 af[4], bfr[4];                                               \
            _Pragma("unroll") for (int f = 0; f < 4; ++f) {                     \
                const int ar = wr * 64 + f * 16 + l15;                          \
                const int br = wc * 64 + f * 16 + l15;                          \
                const int kch = kk * 4 + lg;                                    \
                af[f] = *(const bf16x8*)&Alds[buf][ar][(kch ^ (ar & 7)) * 8];   \
                bfr[f] = *(const bf16x8*)&Blds[buf][br][(kch ^ (br & 7)) * 8];  \
            }                                                                   \
            _Pragma("unroll") for (int mi = 0; mi < 4; ++mi)                    \
                _Pragma("unroll") for (int ni = 0; ni < 4; ++ni)                \
                    acc[mi][ni] = mfma_bf16(af[mi], bfr[ni], acc[mi][ni]);      \
        }                                                                       \
    }

    if constexpr (DBUF == 0) {
        for (int k0 = 0; k0 < K; k0 += 64) {
            STAGE(0, k0);
            __syncthreads();
            COMPUTE(0);
            __syncthreads();
        }
    } else {
        STAGE(0, 0);
        for (int k0 = 0; k0 < K; k0 += 64) {
            const int cur = (k0 >> 6) & 1;
            if (k0 + 64 < K) {
                STAGE(cur ^ 1, k0 + 64);
                asm volatile("s_waitcnt vmcnt(8)" ::: "memory");
            } else {
                asm volatile("s_waitcnt vmcnt(0)" ::: "memory");
            }
            __builtin_amdgcn_sched_barrier(0);
            __builtin_amdgcn_s_barrier();
            __builtin_amdgcn_sched_barrier(0);
            COMPUTE(cur);
            __builtin_amdgcn_s_barrier();
        }
    }
#undef STAGE
#undef COMPUTE

    const int m0 = bm + wr * 64, n0 = bn + wc * 64;
#pragma unroll
    for (int mi = 0; mi < 4; ++mi) {
#pragma unroll
        for (int ni = 0; ni < 4; ++ni) {
            if constexpr (MODE == 0) {
                const int n = n0 + ni * 16 + l15;
                const int which = n >> 10;
                const int hh = (n >> 6) & 15, d = n & 63;
                const int mbase = m0 + mi * 16 + 4 * lg;
                const int bb = mbase >> 11, t = mbase & 2047;
                if (which == 2) {
                    ushort4 pv;
                    pv.x = f2b(acc[mi][ni][0]);
                    pv.y = f2b(acc[mi][ni][1]);
                    pv.z = f2b(acc[mi][ni][2]);
                    pv.w = f2b(acc[mi][ni][3]);
                    *(ushort4*)(vt + (((size_t)(bb * NH + hh)) * DH + d) * TT + t) = pv;
                } else {
                    u16* dst = which == 0 ? oq : ok;
                    const float sc = which == 0 ? 0.18033688f : 1.0f;  // (1/8)*log2(e)
#pragma unroll
                    for (int r = 0; r < 4; ++r)
                        dst[(((size_t)(bb * NH + hh)) * TT + t + r) * DH + d] =
                            f2b(acc[mi][ni][r] * sc);
                }
            } else {
#pragma unroll
                for (int r = 0; r < 4; ++r) {
                    int m = m0 + mi * 16 + 4 * lg + r;
                    int n = n0 + ni * 16 + l15;
                    float v = acc[mi][ni][r];
                    if constexpr (MODE == 1) {
                        size_t o = (size_t)m * N + n;
                        outf[o] = resid[o] + v;
                    } else if constexpr (MODE == 2) {
                        float z = v + bias[n];
                        outbf[(size_t)m * N + n] =
                            f2b(0.5f * z * (1.0f + erff(z * 0.70710678118654752f)));
                    } else {
                        size_t o = (size_t)m * N + n;
                        outf[o] = resid[o] + v + bias[n];
                    }
                }
            }
        }
    }
}

// ---------------- flash attention, causal, swapped-operand MFMA ----------------
// grid (16,32) = 512 blocks, 4 waves. Block handles q-tiles p and 31-p (64 rows, 16/wave).
// Swapped QK^T: s[nf][r] = S[t=kv*64+nf*16+4lg+r][q=qt*64+w*16+l15] -> softmax state lane-local.
// Swapped PV: o[nf][r] = O[q=l15-row][d=nf*16+4lg+r]. P fragments built in-register via
// cvt_pk_bf16 + bpermute shuffles (no P LDS round trip). K/V^T staged via global_load_lds
// + T2 source-swizzle, double-buffered with counted vmcnt(4).
__global__ __launch_bounds__(256) void attn_kernel(const u16* __restrict__ Q,
                                                   const u16* __restrict__ Kg,
                                                   const u16* __restrict__ Vtg,
                                                   u16* __restrict__ O) {
    __shared__ __align__(16) u16 Klds[2][64][64];
    __shared__ __align__(16) u16 Vlds[2][64][64];
    const int tid = threadIdx.x, lane = tid & 63, w = tid >> 6;
    const int l15 = lane & 15, lg = lane >> 4;

    int id = blockIdx.x + (blockIdx.y << 4);
    int sw = (id & 7) * 64 + (id >> 3);  // XCD k -> heads 4k..4k+3
    const int p = sw & 15, bh = sw >> 4;
    const size_t base = (size_t)bh * TT * DH;  // same size for [T][Dh] and [Dh][T]
    const int b = bh >> 4, hh = bh & 15;

    const int srow = tid >> 3, pch = tid & 7;
    const int lc = pch ^ (srow & 7);  // (srow+32)&7 == srow&7

    const int src0 = (((2 * lg) & 3) << 4) | l15;
    const int src1 = src0 + 16;
    const bool hi = (lg >> 1) != 0;

#define ASTAGE(buf, kv)                                                                     \
    {                                                                                       \
        gload_lds16(Kg + base + (size_t)((kv) * 64 + srow) * DH + lc * 8,                   \
                    &Klds[buf][srow][pch * 8]);                                             \
        gload_lds16(Kg + base + (size_t)((kv) * 64 + srow + 32) * DH + lc * 8,              \
                    &Klds[buf][srow + 32][pch * 8]);                                        \
        gload_lds16(Vtg + base + (size_t)srow * TT + (kv) * 64 + lc * 8,                    \
                    &Vlds[buf][srow][pch * 8]);                                             \
        gload_lds16(Vtg + base + (size_t)(srow + 32) * TT + (kv) * 64 + lc * 8,             \
                    &Vlds[buf][srow + 32][pch * 8]);                                        \
    }

    for (int half = 0; half < 2; ++half) {
        const int qt = half ? (31 - p) : p;
        const int nkv = qt + 1;
        const int qrow = qt * 64 + w * 16 + l15;
        uint4 qu0 = *(const uint4*)(Q + base + (size_t)qrow * DH + 8 * lg);
        uint4 qu1 = *(const uint4*)(Q + base + (size_t)qrow * DH + 32 + 8 * lg);
        // force Q-load waits to resolve here (outside the loop)
        asm volatile("" : "+v"(qu0.x), "+v"(qu0.y), "+v"(qu0.z), "+v"(qu0.w),
                          "+v"(qu1.x), "+v"(qu1.y), "+v"(qu1.z), "+v"(qu1.w));
        const bf16x8 qf0 = *(const bf16x8*)&qu0;
        const bf16x8 qf1 = *(const bf16x8*)&qu1;

        ASTAGE(0, 0);

        f32x4 o[4] = {};
        float mrun = -INFINITY, lsum = 0.0f;

        int cur = 0;
        for (int kv = 0; kv < nkv; ++kv) {
            if (kv + 1 < nkv) {
                ASTAGE(cur ^ 1, kv + 1);
                asm volatile("s_waitcnt vmcnt(4)" ::: "memory");
            } else {
                asm volatile("s_waitcnt vmcnt(0)" ::: "memory");
            }
            __builtin_amdgcn_sched_barrier(0);
            __builtin_amdgcn_s_barrier();
            __builtin_amdgcn_sched_barrier(0);

            // S^T = K Q^T
            f32x4 s[4] = {};
#pragma unroll
            for (int nf = 0; nf < 4; ++nf) {
                const int row = nf * 16 + l15;
                bf16x8 kb0 = *(const bf16x8*)&Klds[cur][row][(lg ^ (l15 & 7)) * 8];
                bf16x8 kb1 = *(const bf16x8*)&Klds[cur][row][((4 + lg) ^ (l15 & 7)) * 8];
                s[nf] = mfma_bf16(kb0, qf0, s[nf]);
                s[nf] = mfma_bf16(kb1, qf1, s[nf]);
            }

            if (kv == qt) {  // diagonal tile: causal mask
#pragma unroll
                for (int nf = 0; nf < 4; ++nf) {
                    const int tg = kv * 64 + nf * 16 + 4 * lg;
#pragma unroll
                    for (int r = 0; r < 4; ++r)
                        if (tg + r > qrow) s[nf][r] = -1e30f;
                }
            }

            // row softmax (row q = qrow, lane-local state; base-2, log2e folded into Q)
            f32x4 m4 = s[0];
#pragma unroll
            for (int nf = 1; nf < 4; ++nf) {
                m4[0] = fmaxf(m4[0], s[nf][0]);
                m4[1] = fmaxf(m4[1], s[nf][1]);
                m4[2] = fmaxf(m4[2], s[nf][2]);
                m4[3] = fmaxf(m4[3], s[nf][3]);
            }
            float pmax = fmaxf(fmaxf(m4[0], m4[1]), fmaxf(m4[2], m4[3]));
            pmax = fmaxf(pmax, __shfl_xor(pmax, 16));
            pmax = fmaxf(pmax, __shfl_xor(pmax, 32));
            const float mnew = fmaxf(mrun, pmax);
            const float alpha = exp2f(mrun - mnew);
            mrun = mnew;
            float ps = 0.0f;
#pragma unroll
            for (int nf = 0; nf < 4; ++nf) {
#pragma unroll
                for (int r = 0; r < 4; ++r) {
                    const float pp = exp2f(s[nf][r] - mnew);
                    s[nf][r] = pp;
                    ps += pp;
                }
                o[nf] = o[nf] * alpha;
            }
            lsum = lsum * alpha + ps;

            // pack P rows to bf16 and redistribute into PV B-fragments.
            // pa[kf][j] = P[q=l15][t=kf*32+8*lg+j]; source: lane ((2lg+(j>>2))&3, l15),
            // register pk[2kf+(lg>>1)][j&3 pairs].
            unsigned pk[4][2];
#pragma unroll
            for (int nf = 0; nf < 4; ++nf) {
                pk[nf][0] = cvtpk(s[nf][0], s[nf][1]);
                pk[nf][1] = cvtpk(s[nf][2], s[nf][3]);
            }
            bf16x8 pa[2];
#pragma unroll
            for (int kf = 0; kf < 2; ++kf) {
                unsigned a0 = __shfl((int)pk[2 * kf][0], src0);
                unsigned a1 = __shfl((int)pk[2 * kf][1], src0);
                unsigned a2 = __shfl((int)pk[2 * kf][0], src1);
                unsigned a3 = __shfl((int)pk[2 * kf][1], src1);
                unsigned c0 = __shfl((int)pk[2 * kf + 1][0], src0);
                unsigned c1 = __shfl((int)pk[2 * kf + 1][1], src0);
                unsigned c2 = __shfl((int)pk[2 * kf + 1][0], src1);
                unsigned c3 = __shfl((int)pk[2 * kf + 1][1], src1);
                uint4 wv;
                wv.x = hi ? c0 : a0;
                wv.y = hi ? c1 : a1;
                wv.z = hi ? c2 : a2;
                wv.w = hi ? c3 : a3;
                pa[kf] = *(const bf16x8*)&wv;
            }

            // O^T += V^T P^T
#pragma unroll
            for (int nf = 0; nf < 4; ++nf) {
                const int row = nf * 16 + l15;
                bf16x8 vb0 = *(const bf16x8*)&Vlds[cur][row][(lg ^ (l15 & 7)) * 8];
                bf16x8 vb1 = *(const bf16x8*)&Vlds[cur][row][((4 + lg) ^ (l15 & 7)) * 8];
                o[nf] = mfma_bf16(vb0, pa[0], o[nf]);
                o[nf] = mfma_bf16(vb1, pa[1], o[nf]);
            }

            __builtin_amdgcn_s_barrier();
            cur ^= 1;
        }

        lsum += __shfl_xor(lsum, 16);
        lsum += __shfl_xor(lsum, 32);
        const float linv = 1.0f / lsum;
#pragma unroll
        for (int nf = 0; nf < 4; ++nf) {
            ushort4 pv;
            pv.x = f2b(o[nf][0] * linv);
            pv.y = f2b(o[nf][1] * linv);
            pv.z = f2b(o[nf][2] * linv);
            pv.w = f2b(o[nf][3] * linv);
            *(ushort4*)(O + ((size_t)b * TT + qrow) * DM + hh * DH + nf * 16 + 4 * lg) = pv;
        }
    }
#undef ASTAGE
}

extern "C" void kernel_launch(void* const* d_in, const int* in_sizes, int n_in,
                              void* d_out, int out_size, void* d_ws, size_t ws_size,
                              hipStream_t stream) {
    const float* x = (const float*)d_in[0];
    const float* wqkv = (const float*)d_in[1];
    const float* wout = (const float*)d_in[2];
    const float* ln1g = (const float*)d_in[3];
    const float* ln1b = (const float*)d_in[4];
    const float* ln2g = (const float*)d_in[5];
    const float* ln2b = (const float*)d_in[6];
    const float* w1 = (const float*)d_in[7];
    const float* b1 = (const float*)d_in[8];
    const float* w2 = (const float*)d_in[9];
    const float* b2 = (const float*)d_in[10];
    float* out = (float*)d_out;
    char* ws = (char*)d_ws;

    u16* wqkv_t = (u16*)(ws + 0);          // [3072][1024] bf16
    u16* wout_t = (u16*)(ws + 6291456);    // [1024][1024]
    u16* w1_t   = (u16*)(ws + 8388608);    // [4096][1024]
    u16* w2_t   = (u16*)(ws + 16777216);   // [1024][4096]
    u16* h_bf   = (u16*)(ws + 25165824);   // [4096][1024] (LN1, reused for LN2)
    u16* q_bf   = (u16*)(ws + 33554432);   // [B,H,T,Dh]
    u16* k_bf   = (u16*)(ws + 41943040);   // [B,H,T,Dh]
    u16* vt_bf  = (u16*)(ws + 50331648);   // [B,H,Dh,T]  (V^T)
    u16* at_bf  = (u16*)(ws + 58720256);   // [4096][1024]
    float* x1   = (float*)(ws + 67108864); // [4096][1024] fp32
    u16* ff1_bf = q_bf;                    // aliases q/k/vt/at (dead by FF1): [4096][4096]

    transW<<<dim3(96, 32), 256, 0, stream>>>(wqkv, wqkv_t, 1024, 3072);
    transW<<<dim3(32, 32), 256, 0, stream>>>(wout, wout_t, 1024, 1024);
    transW<<<dim3(128, 32), 256, 0, stream>>>(w1, w1_t, 1024, 4096);
    transW<<<dim3(32, 128), 256, 0, stream>>>(w2, w2_t, 4096, 1024);

    ln_kernel<<<4096, 256, 0, stream>>>(x, ln1g, ln1b, h_bf);

    gemm_kernel<0, 0><<<dim3(24, 32), 256, 0, stream>>>(h_bf, wqkv_t, 4096, 3072, 1024,
                                                        q_bf, k_bf, vt_bf,
                                                        nullptr, nullptr, nullptr, nullptr);

    attn_kernel<<<dim3(16, 32), 256, 0, stream>>>(q_bf, k_bf, vt_bf, at_bf);

    gemm_kernel<1, 1><<<dim3(8, 32), 256, 0, stream>>>(at_bf, wout_t, 4096, 1024, 1024,
                                                       nullptr, nullptr, nullptr,
                                                       x, x1, nullptr, nullptr);

    ln_kernel<<<4096, 256, 0, stream>>>(x1, ln2g, ln2b, h_bf);

    gemm_kernel<2, 0><<<dim3(32, 32), 256, 0, stream>>>(h_bf, w1_t, 4096, 4096, 1024,
                                                        nullptr, nullptr, nullptr,
                                                        nullptr, nullptr, b1, ff1_bf);

    gemm_kernel<3, 1><<<dim3(8, 32), 256, 0, stream>>>(ff1_bf, w2_t, 4096, 1024, 4096,
                                                       nullptr, nullptr, nullptr,
                                                       x1, out, b2, nullptr);
}

// Round 5
// 262.654 us; speedup vs baseline: 1.4353x; 1.0290x over previous
//
#include <hip/hip_runtime.h>
#include <hip/hip_bf16.h>
#include <cstdint>

#define DM 1024
#define DFF 4096
#define NB 2
#define TT 2048
#define NH 16
#define DH 64

typedef unsigned short u16;
typedef __bf16 bf16x8 __attribute__((ext_vector_type(8)));
typedef float f32x4 __attribute__((ext_vector_type(4)));

__device__ __forceinline__ u16 f2b(float f) {
    union { float f; unsigned u; } v; v.f = f;
    unsigned u = v.u;
    return (u16)((u + 0x7FFFu + ((u >> 16) & 1u)) >> 16);
}

__device__ __forceinline__ unsigned cvtpk(float a, float b) {
    unsigned r;
    asm("v_cvt_pk_bf16_f32 %0, %1, %2" : "=v"(r) : "v"(a), "v"(b));
    return r;
}

// gelu(z) = z * sigmoid(2*0.79788456*(z+0.044715 z^3)); exp2-based, ~7 VALU ops.
// max abs err vs exact erf-gelu ~3e-4 (far below bf16 threshold).
__device__ __forceinline__ float gelu_fast(float z) {
    const float u = z * z;
    const float w = z * __builtin_fmaf(u, 0.10294324f, 2.3022082f);
    const float e = exp2f(w);
    const float r = __builtin_amdgcn_rcpf(1.0f + e);
    return z - z * r;
}

__device__ __forceinline__ f32x4 mfma_bf16(bf16x8 a, bf16x8 b, f32x4 c) {
    return __builtin_amdgcn_mfma_f32_16x16x32_bf16(a, b, c, 0, 0, 0);
}

__device__ __forceinline__ void gload_lds16(const void* g, void* l) {
    __builtin_amdgcn_global_load_lds((const __attribute__((address_space(1))) unsigned int*)g,
                                     (__attribute__((address_space(3))) unsigned int*)l, 16, 0, 0);
}

// ---------------- transpose + fp32->bf16 convert: Wt[n][k] = bf16(W[k][n]) ----------------
__global__ __launch_bounds__(256) void transW(const float* __restrict__ W, u16* __restrict__ Wt,
                                              int K, int N) {
    __shared__ float t[32][33];
    int tx = threadIdx.x & 31, ty = threadIdx.x >> 5;
    int k0 = blockIdx.y * 32, n0 = blockIdx.x * 32;
#pragma unroll
    for (int j = 0; j < 4; ++j)
        t[ty + 8 * j][tx] = W[(size_t)(k0 + ty + 8 * j) * N + n0 + tx];
    __syncthreads();
#pragma unroll
    for (int j = 0; j < 4; ++j)
        Wt[(size_t)(n0 + ty + 8 * j) * K + k0 + tx] = f2b(t[tx][ty + 8 * j]);
}

// ---------------- LayerNorm fp32 -> bf16 ----------------
__global__ __launch_bounds__(256) void ln_kernel(const float* __restrict__ X,
                                                 const float* __restrict__ g,
                                                 const float* __restrict__ bt,
                                                 u16* __restrict__ H) {
    int row = blockIdx.x, tid = threadIdx.x;
    float4 v = ((const float4*)(X + (size_t)row * DM))[tid];
    float s = v.x + v.y + v.z + v.w;
    float ss = v.x * v.x + v.y * v.y + v.z * v.z + v.w * v.w;
#pragma unroll
    for (int off = 32; off >= 1; off >>= 1) {
        s += __shfl_xor(s, off);
        ss += __shfl_xor(ss, off);
    }
    __shared__ float sb[8];
    int w = tid >> 6, lane = tid & 63;
    if (lane == 0) { sb[w] = s; sb[4 + w] = ss; }
    __syncthreads();
    s = sb[0] + sb[1] + sb[2] + sb[3];
    ss = sb[4] + sb[5] + sb[6] + sb[7];
    float mu = s * (1.0f / DM);
    float var = ss * (1.0f / DM) - mu * mu;
    float rstd = rsqrtf(var + 1e-5f);
    float4 gv = ((const float4*)g)[tid];
    float4 bv = ((const float4*)bt)[tid];
    uint2 hv;
    hv.x = cvtpk((v.x - mu) * rstd * gv.x + bv.x, (v.y - mu) * rstd * gv.y + bv.y);
    hv.y = cvtpk((v.z - mu) * rstd * gv.z + bv.z, (v.w - mu) * rstd * gv.w + bv.w);
    ((uint2*)(H + (size_t)row * DM))[tid] = hv;
}

// ---------------- bf16 MFMA GEMM ----------------
// T2 swizzle: element (row, chunk) stored at physical chunk^(row&7) (16B chunks, 128B rows).
// DBUF=1: double-buffered, counted vmcnt(8), raw barriers.
// MODE 0: q(scaled)/k -> [B,H,T,Dh]; v -> V^T [B,H,Dh,T] packed. 1: resid+C fp32.
// 2: gelu(C+bias) bf16. 3: resid+C+bias fp32.
template <int MODE, int DBUF>
__global__ __launch_bounds__(256) void gemm_kernel(
    const u16* __restrict__ A, const u16* __restrict__ Bt, int M, int N, int K,
    u16* __restrict__ oq, u16* __restrict__ ok, u16* __restrict__ vt,
    const float* __restrict__ resid, float* __restrict__ outf,
    const float* __restrict__ bias, u16* __restrict__ outbf) {
    __shared__ __align__(16) u16 Alds[DBUF + 1][128][64];
    __shared__ __align__(16) u16 Blds[DBUF + 1][128][64];
    const int tid = threadIdx.x;
    const int lane = tid & 63;
    const int w = tid >> 6;
    const int wr = w >> 1, wc = w & 1;
    int bid = blockIdx.x + gridDim.x * blockIdx.y;
    const int nwg = gridDim.x * gridDim.y;
    bid = (bid & 7) * (nwg >> 3) + (bid >> 3);
    const int bm = (bid / gridDim.x) * 128, bn = (bid % gridDim.x) * 128;
    const int l15 = lane & 15, lg = lane >> 4;
    const int srow = tid >> 3, pch = tid & 7;
    const int lc = pch ^ (srow & 7);

    f32x4 acc[4][4] = {};
    const u16* Ap = A + (size_t)(bm + srow) * K + lc * 8;
    const u16* Bp = Bt + (size_t)(bn + srow) * K + lc * 8;

#define STAGE(buf, k0)                                                          \
    {                                                                           \
        _Pragma("unroll") for (int i = 0; i < 4; ++i) {                         \
            gload_lds16(Ap + (size_t)(32 * i) * K + (k0), &Alds[buf][srow + 32 * i][pch * 8]); \
            gload_lds16(Bp + (size_t)(32 * i) * K + (k0), &Blds[buf][srow + 32 * i][pch * 8]); \
        }                                                                       \
    }

#define COMPUTE(buf)                                                            \
    {                                                                           \
        _Pragma("unroll") for (int kk = 0; kk < 2; ++kk) {                      \
            bf16x8 af[4], bfr[4];                                               \
            _Pragma("unroll") for (int f = 0; f < 4; ++f) {                     \
                const int ar = wr * 64 + f * 16 + l15;                          \
                const int br = wc * 64 + f * 16 + l15;                          \
                const int kch = kk * 4 + lg;                                    \
                af[f] = *(const bf16x8*)&Alds[buf][ar][(kch ^ (ar & 7)) * 8];   \
                bfr[f] = *(const bf16x8*)&Blds[buf][br][(kch ^ (br & 7)) * 8];  \
            }                                                                   \
            _Pragma("unroll") for (int mi = 0; mi < 4; ++mi)                    \
                _Pragma("unroll") for (int ni = 0; ni < 4; ++ni)                \
                    acc[mi][ni] = mfma_bf16(af[mi], bfr[ni], acc[mi][ni]);      \
        }                                                                       \
    }

    if constexpr (DBUF == 0) {
        for (int k0 = 0; k0 < K; k0 += 64) {
            STAGE(0, k0);
            __syncthreads();
            COMPUTE(0);
            __syncthreads();
        }
    } else {
        STAGE(0, 0);
        for (int k0 = 0; k0 < K; k0 += 64) {
            const int cur = (k0 >> 6) & 1;
            if (k0 + 64 < K) {
                STAGE(cur ^ 1, k0 + 64);
                asm volatile("s_waitcnt vmcnt(8)" ::: "memory");
            } else {
                asm volatile("s_waitcnt vmcnt(0)" ::: "memory");
            }
            __builtin_amdgcn_sched_barrier(0);
            __builtin_amdgcn_s_barrier();
            __builtin_amdgcn_sched_barrier(0);
            COMPUTE(cur);
            __builtin_amdgcn_s_barrier();
        }
    }
#undef STAGE
#undef COMPUTE

    const int m0 = bm + wr * 64, n0 = bn + wc * 64;
#pragma unroll
    for (int mi = 0; mi < 4; ++mi) {
#pragma unroll
        for (int ni = 0; ni < 4; ++ni) {
            if constexpr (MODE == 0) {
                const int n = n0 + ni * 16 + l15;
                const int which = n >> 10;
                const int hh = (n >> 6) & 15, d = n & 63;
                const int mbase = m0 + mi * 16 + 4 * lg;
                const int bb = mbase >> 11, t = mbase & 2047;
                if (which == 2) {
                    uint2 pv;
                    pv.x = cvtpk(acc[mi][ni][0], acc[mi][ni][1]);
                    pv.y = cvtpk(acc[mi][ni][2], acc[mi][ni][3]);
                    *(uint2*)(vt + (((size_t)(bb * NH + hh)) * DH + d) * TT + t) = pv;
                } else {
                    u16* dst = which == 0 ? oq : ok;
                    const float sc = which == 0 ? 0.18033688f : 1.0f;  // (1/8)*log2(e)
                    const unsigned p01 = cvtpk(acc[mi][ni][0] * sc, acc[mi][ni][1] * sc);
                    const unsigned p23 = cvtpk(acc[mi][ni][2] * sc, acc[mi][ni][3] * sc);
                    u16* db = dst + (((size_t)(bb * NH + hh)) * TT + t) * DH + d;
                    db[0] = (u16)p01;
                    db[DH] = (u16)(p01 >> 16);
                    db[2 * DH] = (u16)p23;
                    db[3 * DH] = (u16)(p23 >> 16);
                }
            } else if constexpr (MODE == 2) {
                const int n = n0 + ni * 16 + l15;
                const float bn_ = bias[n];
                const float g0 = gelu_fast(acc[mi][ni][0] + bn_);
                const float g1 = gelu_fast(acc[mi][ni][1] + bn_);
                const float g2 = gelu_fast(acc[mi][ni][2] + bn_);
                const float g3 = gelu_fast(acc[mi][ni][3] + bn_);
                const unsigned p01 = cvtpk(g0, g1);
                const unsigned p23 = cvtpk(g2, g3);
                u16* db = outbf + (size_t)(m0 + mi * 16 + 4 * lg) * N + n;
                db[0] = (u16)p01;
                db[N] = (u16)(p01 >> 16);
                db[2 * N] = (u16)p23;
                db[3 * N] = (u16)(p23 >> 16);
            } else {
#pragma unroll
                for (int r = 0; r < 4; ++r) {
                    int m = m0 + mi * 16 + 4 * lg + r;
                    int n = n0 + ni * 16 + l15;
                    float v = acc[mi][ni][r];
                    size_t o = (size_t)m * N + n;
                    if constexpr (MODE == 1) {
                        outf[o] = resid[o] + v;
                    } else {
                        outf[o] = resid[o] + v + bias[n];
                    }
                }
            }
        }
    }
}

// ---------------- flash attention, causal, swapped-operand MFMA ----------------
// grid (16,32) = 512 blocks, 4 waves. Block handles q-tiles p and 31-p (64 rows, 16/wave).
// Swapped QK^T: s[nf][r] = S[t][q=qrow] -> softmax state lane-local. Swapped PV.
// P fragments built in-register via cvt_pk_bf16 + bpermute shuffles. K/V^T staged via
// global_load_lds + T2 source-swizzle, double-buffered with counted vmcnt(4).
__global__ __launch_bounds__(256) void attn_kernel(const u16* __restrict__ Q,
                                                   const u16* __restrict__ Kg,
                                                   const u16* __restrict__ Vtg,
                                                   u16* __restrict__ O) {
    __shared__ __align__(16) u16 Klds[2][64][64];
    __shared__ __align__(16) u16 Vlds[2][64][64];
    const int tid = threadIdx.x, lane = tid & 63, w = tid >> 6;
    const int l15 = lane & 15, lg = lane >> 4;

    int id = blockIdx.x + (blockIdx.y << 4);
    int sw = (id & 7) * 64 + (id >> 3);  // XCD k -> heads 4k..4k+3
    const int p = sw & 15, bh = sw >> 4;
    const size_t base = (size_t)bh * TT * DH;
    const int b = bh >> 4, hh = bh & 15;

    const int srow = tid >> 3, pch = tid & 7;
    const int lc = pch ^ (srow & 7);

    const int src0 = (((2 * lg) & 3) << 4) | l15;
    const int src1 = src0 + 16;
    const bool hi = (lg >> 1) != 0;

#define ASTAGE(buf, kv)                                                                     \
    {                                                                                       \
        gload_lds16(Kg + base + (size_t)((kv) * 64 + srow) * DH + lc * 8,                   \
                    &Klds[buf][srow][pch * 8]);                                             \
        gload_lds16(Kg + base + (size_t)((kv) * 64 + srow + 32) * DH + lc * 8,              \
                    &Klds[buf][srow + 32][pch * 8]);                                        \
        gload_lds16(Vtg + base + (size_t)srow * TT + (kv) * 64 + lc * 8,                    \
                    &Vlds[buf][srow][pch * 8]);                                             \
        gload_lds16(Vtg + base + (size_t)(srow + 32) * TT + (kv) * 64 + lc * 8,             \
                    &Vlds[buf][srow + 32][pch * 8]);                                        \
    }

    for (int half = 0; half < 2; ++half) {
        const int qt = half ? (31 - p) : p;
        const int nkv = qt + 1;
        const int qrow = qt * 64 + w * 16 + l15;
        uint4 qu0 = *(const uint4*)(Q + base + (size_t)qrow * DH + 8 * lg);
        uint4 qu1 = *(const uint4*)(Q + base + (size_t)qrow * DH + 32 + 8 * lg);
        asm volatile("" : "+v"(qu0.x), "+v"(qu0.y), "+v"(qu0.z), "+v"(qu0.w),
                          "+v"(qu1.x), "+v"(qu1.y), "+v"(qu1.z), "+v"(qu1.w));
        const bf16x8 qf0 = *(const bf16x8*)&qu0;
        const bf16x8 qf1 = *(const bf16x8*)&qu1;

        ASTAGE(0, 0);

        f32x4 o[4] = {};
        float mrun = -INFINITY, lsum = 0.0f;

        int cur = 0;
        for (int kv = 0; kv < nkv; ++kv) {
            if (kv + 1 < nkv) {
                ASTAGE(cur ^ 1, kv + 1);
                asm volatile("s_waitcnt vmcnt(4)" ::: "memory");
            } else {
                asm volatile("s_waitcnt vmcnt(0)" ::: "memory");
            }
            __builtin_amdgcn_sched_barrier(0);
            __builtin_amdgcn_s_barrier();
            __builtin_amdgcn_sched_barrier(0);

            // S^T = K Q^T
            f32x4 s[4] = {};
            __builtin_amdgcn_s_setprio(1);
#pragma unroll
            for (int nf = 0; nf < 4; ++nf) {
                const int row = nf * 16 + l15;
                bf16x8 kb0 = *(const bf16x8*)&Klds[cur][row][(lg ^ (l15 & 7)) * 8];
                bf16x8 kb1 = *(const bf16x8*)&Klds[cur][row][((4 + lg) ^ (l15 & 7)) * 8];
                s[nf] = mfma_bf16(kb0, qf0, s[nf]);
                s[nf] = mfma_bf16(kb1, qf1, s[nf]);
            }
            __builtin_amdgcn_s_setprio(0);

            if (kv == qt) {  // diagonal tile: causal mask
#pragma unroll
                for (int nf = 0; nf < 4; ++nf) {
                    const int tg = kv * 64 + nf * 16 + 4 * lg;
#pragma unroll
                    for (int r = 0; r < 4; ++r)
                        if (tg + r > qrow) s[nf][r] = -1e30f;
                }
            }

            // row softmax (lane-local state; base-2, log2e folded into Q scale)
            f32x4 m4 = s[0];
#pragma unroll
            for (int nf = 1; nf < 4; ++nf) {
                m4[0] = fmaxf(m4[0], s[nf][0]);
                m4[1] = fmaxf(m4[1], s[nf][1]);
                m4[2] = fmaxf(m4[2], s[nf][2]);
                m4[3] = fmaxf(m4[3], s[nf][3]);
            }
            float pmax = fmaxf(fmaxf(m4[0], m4[1]), fmaxf(m4[2], m4[3]));
            pmax = fmaxf(pmax, __shfl_xor(pmax, 16));
            pmax = fmaxf(pmax, __shfl_xor(pmax, 32));
            const float mnew = fmaxf(mrun, pmax);
            const float alpha = exp2f(mrun - mnew);
            mrun = mnew;
            float ps = 0.0f;
#pragma unroll
            for (int nf = 0; nf < 4; ++nf) {
#pragma unroll
                for (int r = 0; r < 4; ++r) {
                    const float pp = exp2f(s[nf][r] - mnew);
                    s[nf][r] = pp;
                    ps += pp;
                }
                o[nf] = o[nf] * alpha;
            }
            lsum = lsum * alpha + ps;

            // pack P rows to bf16 and redistribute into PV B-fragments
            unsigned pk[4][2];
#pragma unroll
            for (int nf = 0; nf < 4; ++nf) {
                pk[nf][0] = cvtpk(s[nf][0], s[nf][1]);
                pk[nf][1] = cvtpk(s[nf][2], s[nf][3]);
            }
            bf16x8 pa[2];
#pragma unroll
            for (int kf = 0; kf < 2; ++kf) {
                unsigned a0 = __shfl((int)pk[2 * kf][0], src0);
                unsigned a1 = __shfl((int)pk[2 * kf][1], src0);
                unsigned a2 = __shfl((int)pk[2 * kf][0], src1);
                unsigned a3 = __shfl((int)pk[2 * kf][1], src1);
                unsigned c0 = __shfl((int)pk[2 * kf + 1][0], src0);
                unsigned c1 = __shfl((int)pk[2 * kf + 1][1], src0);
                unsigned c2 = __shfl((int)pk[2 * kf + 1][0], src1);
                unsigned c3 = __shfl((int)pk[2 * kf + 1][1], src1);
                uint4 wv;
                wv.x = hi ? c0 : a0;
                wv.y = hi ? c1 : a1;
                wv.z = hi ? c2 : a2;
                wv.w = hi ? c3 : a3;
                pa[kf] = *(const bf16x8*)&wv;
            }

            // O^T += V^T P^T
            __builtin_amdgcn_s_setprio(1);
#pragma unroll
            for (int nf = 0; nf < 4; ++nf) {
                const int row = nf * 16 + l15;
                bf16x8 vb0 = *(const bf16x8*)&Vlds[cur][row][(lg ^ (l15 & 7)) * 8];
                bf16x8 vb1 = *(const bf16x8*)&Vlds[cur][row][((4 + lg) ^ (l15 & 7)) * 8];
                o[nf] = mfma_bf16(vb0, pa[0], o[nf]);
                o[nf] = mfma_bf16(vb1, pa[1], o[nf]);
            }
            __builtin_amdgcn_s_setprio(0);

            __builtin_amdgcn_s_barrier();
            cur ^= 1;
        }

        lsum += __shfl_xor(lsum, 16);
        lsum += __shfl_xor(lsum, 32);
        const float linv = 1.0f / lsum;
#pragma unroll
        for (int nf = 0; nf < 4; ++nf) {
            uint2 pv;
            pv.x = cvtpk(o[nf][0] * linv, o[nf][1] * linv);
            pv.y = cvtpk(o[nf][2] * linv, o[nf][3] * linv);
            *(uint2*)(O + ((size_t)b * TT + qrow) * DM + hh * DH + nf * 16 + 4 * lg) = pv;
        }
    }
#undef ASTAGE
}

extern "C" void kernel_launch(void* const* d_in, const int* in_sizes, int n_in,
                              void* d_out, int out_size, void* d_ws, size_t ws_size,
                              hipStream_t stream) {
    const float* x = (const float*)d_in[0];
    const float* wqkv = (const float*)d_in[1];
    const float* wout = (const float*)d_in[2];
    const float* ln1g = (const float*)d_in[3];
    const float* ln1b = (const float*)d_in[4];
    const float* ln2g = (const float*)d_in[5];
    const float* ln2b = (const float*)d_in[6];
    const float* w1 = (const float*)d_in[7];
    const float* b1 = (const float*)d_in[8];
    const float* w2 = (const float*)d_in[9];
    const float* b2 = (const float*)d_in[10];
    float* out = (float*)d_out;
    char* ws = (char*)d_ws;

    u16* wqkv_t = (u16*)(ws + 0);          // [3072][1024] bf16
    u16* wout_t = (u16*)(ws + 6291456);    // [1024][1024]
    u16* w1_t   = (u16*)(ws + 8388608);    // [4096][1024]
    u16* w2_t   = (u16*)(ws + 16777216);   // [1024][4096]
    u16* h_bf   = (u16*)(ws + 25165824);   // [4096][1024] (LN1, reused for LN2)
    u16* q_bf   = (u16*)(ws + 33554432);   // [B,H,T,Dh]
    u16* k_bf   = (u16*)(ws + 41943040);   // [B,H,T,Dh]
    u16* vt_bf  = (u16*)(ws + 50331648);   // [B,H,Dh,T]  (V^T)
    u16* at_bf  = (u16*)(ws + 58720256);   // [4096][1024]
    float* x1   = (float*)(ws + 67108864); // [4096][1024] fp32
    u16* ff1_bf = q_bf;                    // aliases q/k/vt/at (dead by FF1): [4096][4096]

    transW<<<dim3(96, 32), 256, 0, stream>>>(wqkv, wqkv_t, 1024, 3072);
    transW<<<dim3(32, 32), 256, 0, stream>>>(wout, wout_t, 1024, 1024);
    transW<<<dim3(128, 32), 256, 0, stream>>>(w1, w1_t, 1024, 4096);
    transW<<<dim3(32, 128), 256, 0, stream>>>(w2, w2_t, 4096, 1024);

    ln_kernel<<<4096, 256, 0, stream>>>(x, ln1g, ln1b, h_bf);

    gemm_kernel<0, 1><<<dim3(24, 32), 256, 0, stream>>>(h_bf, wqkv_t, 4096, 3072, 1024,
                                                        q_bf, k_bf, vt_bf,
                                                        nullptr, nullptr, nullptr, nullptr);

    attn_kernel<<<dim3(16, 32), 256, 0, stream>>>(q_bf, k_bf, vt_bf, at_bf);

    gemm_kernel<1, 1><<<dim3(8, 32), 256, 0, stream>>>(at_bf, wout_t, 4096, 1024, 1024,
                                                       nullptr, nullptr, nullptr,
                                                       x, x1, nullptr, nullptr);

    ln_kernel<<<4096, 256, 0, stream>>>(x1, ln2g, ln2b, h_bf);

    gemm_kernel<2, 1><<<dim3(32, 32), 256, 0, stream>>>(h_bf, w1_t, 4096, 4096, 1024,
                                                        nullptr, nullptr, nullptr,
                                                        nullptr, nullptr, b1, ff1_bf);

    gemm_kernel<3, 1><<<dim3(8, 32), 256, 0, stream>>>(ff1_bf, w2_t, 4096, 1024, 4096,
                                                       nullptr, nullptr, nullptr,
                                                       x1, out, b2, nullptr);
}

// Round 6
// 253.976 us; speedup vs baseline: 1.4844x; 1.0342x over previous
//
#include <hip/hip_runtime.h>
#include <hip/hip_bf16.h>
#include <cstdint>

#define DM 1024
#define DFF 4096
#define NB 2
#define TT 2048
#define NH 16
#define DH 64

typedef unsigned short u16;
typedef __bf16 bf16x8 __attribute__((ext_vector_type(8)));
typedef float f32x4 __attribute__((ext_vector_type(4)));

__device__ __forceinline__ u16 f2b(float f) {
    union { float f; unsigned u; } v; v.f = f;
    unsigned u = v.u;
    return (u16)((u + 0x7FFFu + ((u >> 16) & 1u)) >> 16);
}

__device__ __forceinline__ unsigned cvtpk(float a, float b) {
    unsigned r;
    asm("v_cvt_pk_bf16_f32 %0, %1, %2" : "=v"(r) : "v"(a), "v"(b));
    return r;
}

// gelu(z) = z * sigmoid(2*0.79788456*(z+0.044715 z^3)); exp2-based, ~7 VALU ops.
__device__ __forceinline__ float gelu_fast(float z) {
    const float u = z * z;
    const float w = z * __builtin_fmaf(u, 0.10294324f, 2.3022082f);
    const float e = exp2f(w);
    const float r = __builtin_amdgcn_rcpf(1.0f + e);
    return z - z * r;
}

__device__ __forceinline__ f32x4 mfma_bf16(bf16x8 a, bf16x8 b, f32x4 c) {
    return __builtin_amdgcn_mfma_f32_16x16x32_bf16(a, b, c, 0, 0, 0);
}

__device__ __forceinline__ void gload_lds16(const void* g, void* l) {
    __builtin_amdgcn_global_load_lds((const __attribute__((address_space(1))) unsigned int*)g,
                                     (__attribute__((address_space(3))) unsigned int*)l, 16, 0, 0);
}

// ---------------- transpose + fp32->bf16 convert: Wt[n][k] = bf16(W[k][n]) ----------------
__global__ __launch_bounds__(256) void transW(const float* __restrict__ W, u16* __restrict__ Wt,
                                              int K, int N) {
    __shared__ float t[32][33];
    int tx = threadIdx.x & 31, ty = threadIdx.x >> 5;
    int k0 = blockIdx.y * 32, n0 = blockIdx.x * 32;
#pragma unroll
    for (int j = 0; j < 4; ++j)
        t[ty + 8 * j][tx] = W[(size_t)(k0 + ty + 8 * j) * N + n0 + tx];
    __syncthreads();
#pragma unroll
    for (int j = 0; j < 4; ++j)
        Wt[(size_t)(n0 + ty + 8 * j) * K + k0 + tx] = f2b(t[tx][ty + 8 * j]);
}

// ---------------- LayerNorm fp32 -> bf16 ----------------
__global__ __launch_bounds__(256) void ln_kernel(const float* __restrict__ X,
                                                 const float* __restrict__ g,
                                                 const float* __restrict__ bt,
                                                 u16* __restrict__ H) {
    int row = blockIdx.x, tid = threadIdx.x;
    float4 v = ((const float4*)(X + (size_t)row * DM))[tid];
    float s = v.x + v.y + v.z + v.w;
    float ss = v.x * v.x + v.y * v.y + v.z * v.z + v.w * v.w;
#pragma unroll
    for (int off = 32; off >= 1; off >>= 1) {
        s += __shfl_xor(s, off);
        ss += __shfl_xor(ss, off);
    }
    __shared__ float sb[8];
    int w = tid >> 6, lane = tid & 63;
    if (lane == 0) { sb[w] = s; sb[4 + w] = ss; }
    __syncthreads();
    s = sb[0] + sb[1] + sb[2] + sb[3];
    ss = sb[4] + sb[5] + sb[6] + sb[7];
    float mu = s * (1.0f / DM);
    float var = ss * (1.0f / DM) - mu * mu;
    float rstd = rsqrtf(var + 1e-5f);
    float4 gv = ((const float4*)g)[tid];
    float4 bv = ((const float4*)bt)[tid];
    uint2 hv;
    hv.x = cvtpk((v.x - mu) * rstd * gv.x + bv.x, (v.y - mu) * rstd * gv.y + bv.y);
    hv.y = cvtpk((v.z - mu) * rstd * gv.z + bv.z, (v.w - mu) * rstd * gv.w + bv.w);
    ((uint2*)(H + (size_t)row * DM))[tid] = hv;
}

// ---------------- elementwise add: out += part ----------------
__global__ __launch_bounds__(256) void add_kernel(float* __restrict__ out,
                                                  const float* __restrict__ part, int n4) {
    int idx = blockIdx.x * 256 + threadIdx.x;
    const int stride = gridDim.x * 256;
    for (; idx < n4; idx += stride) {
        float4 a = ((const float4*)out)[idx];
        float4 p = ((const float4*)part)[idx];
        a.x += p.x; a.y += p.y; a.z += p.z; a.w += p.w;
        ((float4*)out)[idx] = a;
    }
}

// ---------------- bf16 MFMA GEMM ----------------
// T2 swizzle: element (row, chunk) stored at physical chunk^(row&7) (16B chunks, 128B rows).
// DBUF=1: double-buffered, counted vmcnt(8), raw barriers.
// SPLIT=1: gridDim.y = 2*(M/128); upper half computes K-half 1 -> raw partial to `part`.
// MODE 0: q(scaled)/k -> [B,H,T,Dh]; v -> V^T [B,H,Dh,T]. 1: resid+C fp32.
// 2: gelu(C+bias) bf16. 3: resid+C+bias fp32.
template <int MODE, int DBUF, int SPLIT>
__global__ __launch_bounds__(256) void gemm_kernel(
    const u16* __restrict__ A, const u16* __restrict__ Bt, int M, int N, int K,
    u16* __restrict__ oq, u16* __restrict__ ok, u16* __restrict__ vt,
    const float* __restrict__ resid, float* __restrict__ outf,
    const float* __restrict__ bias, u16* __restrict__ outbf,
    float* __restrict__ part) {
    __shared__ __align__(16) u16 Alds[DBUF + 1][128][64];
    __shared__ __align__(16) u16 Blds[DBUF + 1][128][64];
    const int tid = threadIdx.x;
    const int lane = tid & 63;
    const int w = tid >> 6;
    const int wr = w >> 1, wc = w & 1;
    int bid = blockIdx.x + gridDim.x * blockIdx.y;
    const int nwg = gridDim.x * gridDim.y;
    bid = (bid & 7) * (nwg >> 3) + (bid >> 3);
    int mrow = bid / gridDim.x;
    int ks = 0;
    if constexpr (SPLIT) {
        const int mtiles = (nwg / gridDim.x) >> 1;
        ks = mrow >= mtiles;
        mrow -= ks * mtiles;
    }
    const int bm = mrow * 128, bn = (bid % gridDim.x) * 128;
    const int kbeg = SPLIT ? ks * (K >> 1) : 0;
    const int kend = SPLIT ? kbeg + (K >> 1) : K;
    const int l15 = lane & 15, lg = lane >> 4;
    const int srow = tid >> 3, pch = tid & 7;
    const int lc = pch ^ (srow & 7);

    f32x4 acc[4][4] = {};
    const u16* Ap = A + (size_t)(bm + srow) * K + lc * 8;
    const u16* Bp = Bt + (size_t)(bn + srow) * K + lc * 8;

#define STAGE(buf, k0)                                                          \
    {                                                                           \
        _Pragma("unroll") for (int i = 0; i < 4; ++i) {                         \
            gload_lds16(Ap + (size_t)(32 * i) * K + (k0), &Alds[buf][srow + 32 * i][pch * 8]); \
            gload_lds16(Bp + (size_t)(32 * i) * K + (k0), &Blds[buf][srow + 32 * i][pch * 8]); \
        }                                                                       \
    }

#define COMPUTE(buf)                                                            \
    {                                                                           \
        _Pragma("unroll") for (int kk = 0; kk < 2; ++kk) {                      \
            bf16x8 af[4], bfr[4];                                               \
            _Pragma("unroll") for (int f = 0; f < 4; ++f) {                     \
                const int ar = wr * 64 + f * 16 + l15;                          \
                const int br = wc * 64 + f * 16 + l15;                          \
                const int kch = kk * 4 + lg;                                    \
                af[f] = *(const bf16x8*)&Alds[buf][ar][(kch ^ (ar & 7)) * 8];   \
                bfr[f] = *(const bf16x8*)&Blds[buf][br][(kch ^ (br & 7)) * 8];  \
            }                                                                   \
            _Pragma("unroll") for (int mi = 0; mi < 4; ++mi)                    \
                _Pragma("unroll") for (int ni = 0; ni < 4; ++ni)                \
                    acc[mi][ni] = mfma_bf16(af[mi], bfr[ni], acc[mi][ni]);      \
        }                                                                       \
    }

    if constexpr (DBUF == 0) {
        for (int k0 = kbeg; k0 < kend; k0 += 64) {
            STAGE(0, k0);
            __syncthreads();
            COMPUTE(0);
            __syncthreads();
        }
    } else {
        STAGE(0, kbeg);
        for (int k0 = kbeg; k0 < kend; k0 += 64) {
            const int cur = ((k0 - kbeg) >> 6) & 1;
            if (k0 + 64 < kend) {
                STAGE(cur ^ 1, k0 + 64);
                asm volatile("s_waitcnt vmcnt(8)" ::: "memory");
            } else {
                asm volatile("s_waitcnt vmcnt(0)" ::: "memory");
            }
            __builtin_amdgcn_sched_barrier(0);
            __builtin_amdgcn_s_barrier();
            __builtin_amdgcn_sched_barrier(0);
            COMPUTE(cur);
            __builtin_amdgcn_s_barrier();
        }
    }
#undef STAGE
#undef COMPUTE

    const int m0 = bm + wr * 64, n0 = bn + wc * 64;
#pragma unroll
    for (int mi = 0; mi < 4; ++mi) {
#pragma unroll
        for (int ni = 0; ni < 4; ++ni) {
            if constexpr (MODE == 0) {
                const int n = n0 + ni * 16 + l15;
                const int which = n >> 10;
                const int hh = (n >> 6) & 15, d = n & 63;
                const int mbase = m0 + mi * 16 + 4 * lg;
                const int bb = mbase >> 11, t = mbase & 2047;
                if (which == 2) {
                    uint2 pv;
                    pv.x = cvtpk(acc[mi][ni][0], acc[mi][ni][1]);
                    pv.y = cvtpk(acc[mi][ni][2], acc[mi][ni][3]);
                    *(uint2*)(vt + (((size_t)(bb * NH + hh)) * DH + d) * TT + t) = pv;
                } else {
                    u16* dst = which == 0 ? oq : ok;
                    const float sc = which == 0 ? 0.18033688f : 1.0f;  // (1/8)*log2(e)
                    const unsigned p01 = cvtpk(acc[mi][ni][0] * sc, acc[mi][ni][1] * sc);
                    const unsigned p23 = cvtpk(acc[mi][ni][2] * sc, acc[mi][ni][3] * sc);
                    u16* db = dst + (((size_t)(bb * NH + hh)) * TT + t) * DH + d;
                    db[0] = (u16)p01;
                    db[DH] = (u16)(p01 >> 16);
                    db[2 * DH] = (u16)p23;
                    db[3 * DH] = (u16)(p23 >> 16);
                }
            } else if constexpr (MODE == 2) {
                const int n = n0 + ni * 16 + l15;
                const float bn_ = bias[n];
                const float g0 = gelu_fast(acc[mi][ni][0] + bn_);
                const float g1 = gelu_fast(acc[mi][ni][1] + bn_);
                const float g2 = gelu_fast(acc[mi][ni][2] + bn_);
                const float g3 = gelu_fast(acc[mi][ni][3] + bn_);
                const unsigned p01 = cvtpk(g0, g1);
                const unsigned p23 = cvtpk(g2, g3);
                u16* db = outbf + (size_t)(m0 + mi * 16 + 4 * lg) * N + n;
                db[0] = (u16)p01;
                db[N] = (u16)(p01 >> 16);
                db[2 * N] = (u16)p23;
                db[3 * N] = (u16)(p23 >> 16);
            } else {
#pragma unroll
                for (int r = 0; r < 4; ++r) {
                    int m = m0 + mi * 16 + 4 * lg + r;
                    int n = n0 + ni * 16 + l15;
                    float v = acc[mi][ni][r];
                    size_t o = (size_t)m * N + n;
                    if constexpr (MODE == 1) {
                        outf[o] = resid[o] + v;
                    } else {
                        if (SPLIT && ks == 1)
                            part[o] = v;
                        else
                            outf[o] = resid[o] + v + bias[n];
                    }
                }
            }
        }
    }
}

// ---------------- flash attention, causal, swapped-operand MFMA ----------------
__global__ __launch_bounds__(256) void attn_kernel(const u16* __restrict__ Q,
                                                   const u16* __restrict__ Kg,
                                                   const u16* __restrict__ Vtg,
                                                   u16* __restrict__ O) {
    __shared__ __align__(16) u16 Klds[2][64][64];
    __shared__ __align__(16) u16 Vlds[2][64][64];
    const int tid = threadIdx.x, lane = tid & 63, w = tid >> 6;
    const int l15 = lane & 15, lg = lane >> 4;

    int id = blockIdx.x + (blockIdx.y << 4);
    int sw = (id & 7) * 64 + (id >> 3);  // XCD k -> heads 4k..4k+3
    const int p = sw & 15, bh = sw >> 4;
    const size_t base = (size_t)bh * TT * DH;
    const int b = bh >> 4, hh = bh & 15;

    const int srow = tid >> 3, pch = tid & 7;
    const int lc = pch ^ (srow & 7);

    const int src0 = (((2 * lg) & 3) << 4) | l15;
    const int src1 = src0 + 16;
    const bool hi = (lg >> 1) != 0;

#define ASTAGE(buf, kv)                                                                     \
    {                                                                                       \
        gload_lds16(Kg + base + (size_t)((kv) * 64 + srow) * DH + lc * 8,                   \
                    &Klds[buf][srow][pch * 8]);                                             \
        gload_lds16(Kg + base + (size_t)((kv) * 64 + srow + 32) * DH + lc * 8,              \
                    &Klds[buf][srow + 32][pch * 8]);                                        \
        gload_lds16(Vtg + base + (size_t)srow * TT + (kv) * 64 + lc * 8,                    \
                    &Vlds[buf][srow][pch * 8]);                                             \
        gload_lds16(Vtg + base + (size_t)(srow + 32) * TT + (kv) * 64 + lc * 8,             \
                    &Vlds[buf][srow + 32][pch * 8]);                                        \
    }

    for (int half = 0; half < 2; ++half) {
        const int qt = half ? (31 - p) : p;
        const int nkv = qt + 1;
        const int qrow = qt * 64 + w * 16 + l15;
        uint4 qu0 = *(const uint4*)(Q + base + (size_t)qrow * DH + 8 * lg);
        uint4 qu1 = *(const uint4*)(Q + base + (size_t)qrow * DH + 32 + 8 * lg);
        asm volatile("" : "+v"(qu0.x), "+v"(qu0.y), "+v"(qu0.z), "+v"(qu0.w),
                          "+v"(qu1.x), "+v"(qu1.y), "+v"(qu1.z), "+v"(qu1.w));
        const bf16x8 qf0 = *(const bf16x8*)&qu0;
        const bf16x8 qf1 = *(const bf16x8*)&qu1;

        ASTAGE(0, 0);

        f32x4 o[4] = {};
        float mrun = -INFINITY, lsum = 0.0f;

        int cur = 0;
        for (int kv = 0; kv < nkv; ++kv) {
            if (kv + 1 < nkv) {
                ASTAGE(cur ^ 1, kv + 1);
                asm volatile("s_waitcnt vmcnt(4)" ::: "memory");
            } else {
                asm volatile("s_waitcnt vmcnt(0)" ::: "memory");
            }
            __builtin_amdgcn_sched_barrier(0);
            __builtin_amdgcn_s_barrier();
            __builtin_amdgcn_sched_barrier(0);

            // S^T = K Q^T
            f32x4 s[4] = {};
            __builtin_amdgcn_s_setprio(1);
#pragma unroll
            for (int nf = 0; nf < 4; ++nf) {
                const int row = nf * 16 + l15;
                bf16x8 kb0 = *(const bf16x8*)&Klds[cur][row][(lg ^ (l15 & 7)) * 8];
                bf16x8 kb1 = *(const bf16x8*)&Klds[cur][row][((4 + lg) ^ (l15 & 7)) * 8];
                s[nf] = mfma_bf16(kb0, qf0, s[nf]);
                s[nf] = mfma_bf16(kb1, qf1, s[nf]);
            }
            __builtin_amdgcn_s_setprio(0);

            if (kv == qt) {  // diagonal tile: causal mask
#pragma unroll
                for (int nf = 0; nf < 4; ++nf) {
                    const int tg = kv * 64 + nf * 16 + 4 * lg;
#pragma unroll
                    for (int r = 0; r < 4; ++r)
                        if (tg + r > qrow) s[nf][r] = -1e30f;
                }
            }

            // row softmax (lane-local state; base-2, log2e folded into Q scale)
            // T13 defer-max: keep old m while pmax <= mrun+8 (P bounded by 2^8).
            f32x4 m4 = s[0];
#pragma unroll
            for (int nf = 1; nf < 4; ++nf) {
                m4[0] = fmaxf(m4[0], s[nf][0]);
                m4[1] = fmaxf(m4[1], s[nf][1]);
                m4[2] = fmaxf(m4[2], s[nf][2]);
                m4[3] = fmaxf(m4[3], s[nf][3]);
            }
            float pmax = fmaxf(fmaxf(m4[0], m4[1]), fmaxf(m4[2], m4[3]));
            pmax = fmaxf(pmax, __shfl_xor(pmax, 16));
            pmax = fmaxf(pmax, __shfl_xor(pmax, 32));
            if (!__all(pmax <= mrun + 8.0f)) {
                const float mnew = fmaxf(mrun, pmax);
                const float alpha = exp2f(mrun - mnew);
                mrun = mnew;
#pragma unroll
                for (int nf = 0; nf < 4; ++nf) o[nf] = o[nf] * alpha;
                lsum *= alpha;
            }
            float ps = 0.0f;
#pragma unroll
            for (int nf = 0; nf < 4; ++nf) {
#pragma unroll
                for (int r = 0; r < 4; ++r) {
                    const float pp = exp2f(s[nf][r] - mrun);
                    s[nf][r] = pp;
                    ps += pp;
                }
            }
            lsum += ps;

            // pack P rows to bf16 and redistribute into PV B-fragments
            unsigned pk[4][2];
#pragma unroll
            for (int nf = 0; nf < 4; ++nf) {
                pk[nf][0] = cvtpk(s[nf][0], s[nf][1]);
                pk[nf][1] = cvtpk(s[nf][2], s[nf][3]);
            }
            bf16x8 pa[2];
#pragma unroll
            for (int kf = 0; kf < 2; ++kf) {
                unsigned a0 = __shfl((int)pk[2 * kf][0], src0);
                unsigned a1 = __shfl((int)pk[2 * kf][1], src0);
                unsigned a2 = __shfl((int)pk[2 * kf][0], src1);
                unsigned a3 = __shfl((int)pk[2 * kf][1], src1);
                unsigned c0 = __shfl((int)pk[2 * kf + 1][0], src0);
                unsigned c1 = __shfl((int)pk[2 * kf + 1][1], src0);
                unsigned c2 = __shfl((int)pk[2 * kf + 1][0], src1);
                unsigned c3 = __shfl((int)pk[2 * kf + 1][1], src1);
                uint4 wv;
                wv.x = hi ? c0 : a0;
                wv.y = hi ? c1 : a1;
                wv.z = hi ? c2 : a2;
                wv.w = hi ? c3 : a3;
                pa[kf] = *(const bf16x8*)&wv;
            }

            // O^T += V^T P^T
            __builtin_amdgcn_s_setprio(1);
#pragma unroll
            for (int nf = 0; nf < 4; ++nf) {
                const int row = nf * 16 + l15;
                bf16x8 vb0 = *(const bf16x8*)&Vlds[cur][row][(lg ^ (l15 & 7)) * 8];
                bf16x8 vb1 = *(const bf16x8*)&Vlds[cur][row][((4 + lg) ^ (l15 & 7)) * 8];
                o[nf] = mfma_bf16(vb0, pa[0], o[nf]);
                o[nf] = mfma_bf16(vb1, pa[1], o[nf]);
            }
            __builtin_amdgcn_s_setprio(0);

            __builtin_amdgcn_s_barrier();
            cur ^= 1;
        }

        lsum += __shfl_xor(lsum, 16);
        lsum += __shfl_xor(lsum, 32);
        const float linv = 1.0f / lsum;
#pragma unroll
        for (int nf = 0; nf < 4; ++nf) {
            uint2 pv;
            pv.x = cvtpk(o[nf][0] * linv, o[nf][1] * linv);
            pv.y = cvtpk(o[nf][2] * linv, o[nf][3] * linv);
            *(uint2*)(O + ((size_t)b * TT + qrow) * DM + hh * DH + nf * 16 + 4 * lg) = pv;
        }
    }
#undef ASTAGE
}

extern "C" void kernel_launch(void* const* d_in, const int* in_sizes, int n_in,
                              void* d_out, int out_size, void* d_ws, size_t ws_size,
                              hipStream_t stream) {
    const float* x = (const float*)d_in[0];
    const float* wqkv = (const float*)d_in[1];
    const float* wout = (const float*)d_in[2];
    const float* ln1g = (const float*)d_in[3];
    const float* ln1b = (const float*)d_in[4];
    const float* ln2g = (const float*)d_in[5];
    const float* ln2b = (const float*)d_in[6];
    const float* w1 = (const float*)d_in[7];
    const float* b1 = (const float*)d_in[8];
    const float* w2 = (const float*)d_in[9];
    const float* b2 = (const float*)d_in[10];
    float* out = (float*)d_out;
    char* ws = (char*)d_ws;

    u16* wqkv_t = (u16*)(ws + 0);          // [3072][1024] bf16 (dead by FF2)
    u16* wout_t = (u16*)(ws + 6291456);    // [1024][1024]      (dead by FF2)
    u16* w1_t   = (u16*)(ws + 8388608);    // [4096][1024]      (dead by FF2)
    u16* w2_t   = (u16*)(ws + 16777216);   // [1024][4096]
    u16* h_bf   = (u16*)(ws + 25165824);   // [4096][1024] (LN1, reused for LN2)
    u16* q_bf   = (u16*)(ws + 33554432);   // [B,H,T,Dh]
    u16* k_bf   = (u16*)(ws + 41943040);   // [B,H,T,Dh]
    u16* vt_bf  = (u16*)(ws + 50331648);   // [B,H,Dh,T]  (V^T)
    u16* at_bf  = (u16*)(ws + 58720256);   // [4096][1024]
    float* x1   = (float*)(ws + 67108864); // [4096][1024] fp32
    u16* ff1_bf = q_bf;                    // aliases q/k/vt/at (dead by FF1): [4096][4096]
    float* p1   = (float*)(ws + 0);        // FF2 K-half-1 partial [4096][1024] fp32 (16 MB)

    transW<<<dim3(96, 32), 256, 0, stream>>>(wqkv, wqkv_t, 1024, 3072);
    transW<<<dim3(32, 32), 256, 0, stream>>>(wout, wout_t, 1024, 1024);
    transW<<<dim3(128, 32), 256, 0, stream>>>(w1, w1_t, 1024, 4096);
    transW<<<dim3(32, 128), 256, 0, stream>>>(w2, w2_t, 4096, 1024);

    ln_kernel<<<4096, 256, 0, stream>>>(x, ln1g, ln1b, h_bf);

    gemm_kernel<0, 1, 0><<<dim3(24, 32), 256, 0, stream>>>(h_bf, wqkv_t, 4096, 3072, 1024,
                                                           q_bf, k_bf, vt_bf,
                                                           nullptr, nullptr, nullptr, nullptr,
                                                           nullptr);

    attn_kernel<<<dim3(16, 32), 256, 0, stream>>>(q_bf, k_bf, vt_bf, at_bf);

    gemm_kernel<1, 1, 0><<<dim3(8, 32), 256, 0, stream>>>(at_bf, wout_t, 4096, 1024, 1024,
                                                          nullptr, nullptr, nullptr,
                                                          x, x1, nullptr, nullptr, nullptr);

    ln_kernel<<<4096, 256, 0, stream>>>(x1, ln2g, ln2b, h_bf);

    gemm_kernel<2, 1, 0><<<dim3(32, 32), 256, 0, stream>>>(h_bf, w1_t, 4096, 4096, 1024,
                                                           nullptr, nullptr, nullptr,
                                                           nullptr, nullptr, b1, ff1_bf,
                                                           nullptr);

    gemm_kernel<3, 1, 1><<<dim3(8, 64), 256, 0, stream>>>(ff1_bf, w2_t, 4096, 1024, 4096,
                                                          nullptr, nullptr, nullptr,
                                                          x1, out, b2, nullptr, p1);

    add_kernel<<<2048, 256, 0, stream>>>(out, p1, 4096 * 1024 / 4);
}

// Round 7
// 244.565 us; speedup vs baseline: 1.5415x; 1.0385x over previous
//
#include <hip/hip_runtime.h>
#include <hip/hip_bf16.h>
#include <cstdint>

#define DM 1024
#define DFF 4096
#define NB 2
#define TT 2048
#define NH 16
#define DH 64

typedef unsigned short u16;
typedef __bf16 bf16x8 __attribute__((ext_vector_type(8)));
typedef float f32x4 __attribute__((ext_vector_type(4)));

__device__ __forceinline__ u16 f2b(float f) {
    union { float f; unsigned u; } v; v.f = f;
    unsigned u = v.u;
    return (u16)((u + 0x7FFFu + ((u >> 16) & 1u)) >> 16);
}

__device__ __forceinline__ unsigned cvtpk(float a, float b) {
    unsigned r;
    asm("v_cvt_pk_bf16_f32 %0, %1, %2" : "=v"(r) : "v"(a), "v"(b));
    return r;
}

// gelu(z) = z * sigmoid(2*0.79788456*(z+0.044715 z^3)); exp2-based, ~7 VALU ops.
__device__ __forceinline__ float gelu_fast(float z) {
    const float u = z * z;
    const float w = z * __builtin_fmaf(u, 0.10294324f, 2.3022082f);
    const float e = exp2f(w);
    const float r = __builtin_amdgcn_rcpf(1.0f + e);
    return z - z * r;
}

__device__ __forceinline__ f32x4 mfma_bf16(bf16x8 a, bf16x8 b, f32x4 c) {
    return __builtin_amdgcn_mfma_f32_16x16x32_bf16(a, b, c, 0, 0, 0);
}

__device__ __forceinline__ void gload_lds16(const void* g, void* l) {
    __builtin_amdgcn_global_load_lds((const __attribute__((address_space(1))) unsigned int*)g,
                                     (__attribute__((address_space(3))) unsigned int*)l, 16, 0, 0);
}

// ---------------- transpose + fp32->bf16 convert: Wt[n][k] = bf16(W[k][n]) ----------------
__global__ __launch_bounds__(256) void transW(const float* __restrict__ W, u16* __restrict__ Wt,
                                              int K, int N) {
    __shared__ float t[32][33];
    int tx = threadIdx.x & 31, ty = threadIdx.x >> 5;
    int k0 = blockIdx.y * 32, n0 = blockIdx.x * 32;
#pragma unroll
    for (int j = 0; j < 4; ++j)
        t[ty + 8 * j][tx] = W[(size_t)(k0 + ty + 8 * j) * N + n0 + tx];
    __syncthreads();
#pragma unroll
    for (int j = 0; j < 4; ++j)
        Wt[(size_t)(n0 + ty + 8 * j) * K + k0 + tx] = f2b(t[tx][ty + 8 * j]);
}

// ---------------- LayerNorm fp32 -> bf16 ----------------
__global__ __launch_bounds__(256) void ln_kernel(const float* __restrict__ X,
                                                 const float* __restrict__ g,
                                                 const float* __restrict__ bt,
                                                 u16* __restrict__ H) {
    int row = blockIdx.x, tid = threadIdx.x;
    float4 v = ((const float4*)(X + (size_t)row * DM))[tid];
    float s = v.x + v.y + v.z + v.w;
    float ss = v.x * v.x + v.y * v.y + v.z * v.z + v.w * v.w;
#pragma unroll
    for (int off = 32; off >= 1; off >>= 1) {
        s += __shfl_xor(s, off);
        ss += __shfl_xor(ss, off);
    }
    __shared__ float sb[8];
    int w = tid >> 6, lane = tid & 63;
    if (lane == 0) { sb[w] = s; sb[4 + w] = ss; }
    __syncthreads();
    s = sb[0] + sb[1] + sb[2] + sb[3];
    ss = sb[4] + sb[5] + sb[6] + sb[7];
    float mu = s * (1.0f / DM);
    float var = ss * (1.0f / DM) - mu * mu;
    float rstd = rsqrtf(var + 1e-5f);
    float4 gv = ((const float4*)g)[tid];
    float4 bv = ((const float4*)bt)[tid];
    uint2 hv;
    hv.x = cvtpk((v.x - mu) * rstd * gv.x + bv.x, (v.y - mu) * rstd * gv.y + bv.y);
    hv.y = cvtpk((v.z - mu) * rstd * gv.z + bv.z, (v.w - mu) * rstd * gv.w + bv.w);
    ((uint2*)(H + (size_t)row * DM))[tid] = hv;
}

// ---------------- elementwise add: out += part ----------------
__global__ __launch_bounds__(256) void add_kernel(float* __restrict__ out,
                                                  const float* __restrict__ part, int n4) {
    int idx = blockIdx.x * 256 + threadIdx.x;
    const int stride = gridDim.x * 256;
    for (; idx < n4; idx += stride) {
        float4 a = ((const float4*)out)[idx];
        float4 p = ((const float4*)part)[idx];
        a.x += p.x; a.y += p.y; a.z += p.z; a.w += p.w;
        ((float4*)out)[idx] = a;
    }
}

// ---------------- bf16 MFMA GEMM ----------------
// T2 swizzle: element (row, chunk) stored at physical chunk^(row&7) (16B chunks, 128B rows).
// DBUF=1: double-buffered, counted vmcnt(8), raw barriers.
// SPLIT=1: gridDim.y = 2*(M/128); upper half computes K-half 1 -> raw partial to `part`.
// MODE 0: q(scaled)/k -> [B,H,T,Dh]; v -> V^T [B,H,Dh,T]. 1: resid+C fp32.
// 2: gelu(C+bias) bf16. 3: resid+C+bias fp32.
template <int MODE, int DBUF, int SPLIT>
__global__ __launch_bounds__(256) void gemm_kernel(
    const u16* __restrict__ A, const u16* __restrict__ Bt, int M, int N, int K,
    u16* __restrict__ oq, u16* __restrict__ ok, u16* __restrict__ vt,
    const float* __restrict__ resid, float* __restrict__ outf,
    const float* __restrict__ bias, u16* __restrict__ outbf,
    float* __restrict__ part) {
    __shared__ __align__(16) u16 Alds[DBUF + 1][128][64];
    __shared__ __align__(16) u16 Blds[DBUF + 1][128][64];
    const int tid = threadIdx.x;
    const int lane = tid & 63;
    const int w = tid >> 6;
    const int wr = w >> 1, wc = w & 1;
    int bid = blockIdx.x + gridDim.x * blockIdx.y;
    const int nwg = gridDim.x * gridDim.y;
    bid = (bid & 7) * (nwg >> 3) + (bid >> 3);
    int mrow = bid / gridDim.x;
    int ks = 0;
    if constexpr (SPLIT) {
        const int mtiles = (nwg / gridDim.x) >> 1;
        ks = mrow >= mtiles;
        mrow -= ks * mtiles;
    }
    const int bm = mrow * 128, bn = (bid % gridDim.x) * 128;
    const int kbeg = SPLIT ? ks * (K >> 1) : 0;
    const int kend = SPLIT ? kbeg + (K >> 1) : K;
    const int l15 = lane & 15, lg = lane >> 4;
    const int srow = tid >> 3, pch = tid & 7;
    const int lc = pch ^ (srow & 7);

    f32x4 acc[4][4] = {};
    const u16* Ap = A + (size_t)(bm + srow) * K + lc * 8;
    const u16* Bp = Bt + (size_t)(bn + srow) * K + lc * 8;

#define STAGE(buf, k0)                                                          \
    {                                                                           \
        _Pragma("unroll") for (int i = 0; i < 4; ++i) {                         \
            gload_lds16(Ap + (size_t)(32 * i) * K + (k0), &Alds[buf][srow + 32 * i][pch * 8]); \
            gload_lds16(Bp + (size_t)(32 * i) * K + (k0), &Blds[buf][srow + 32 * i][pch * 8]); \
        }                                                                       \
    }

#define COMPUTE(buf)                                                            \
    {                                                                           \
        _Pragma("unroll") for (int kk = 0; kk < 2; ++kk) {                      \
            bf16x8 af[4], bfr[4];                                               \
            _Pragma("unroll") for (int f = 0; f < 4; ++f) {                     \
                const int ar = wr * 64 + f * 16 + l15;                          \
                const int br = wc * 64 + f * 16 + l15;                          \
                const int kch = kk * 4 + lg;                                    \
                af[f] = *(const bf16x8*)&Alds[buf][ar][(kch ^ (ar & 7)) * 8];   \
                bfr[f] = *(const bf16x8*)&Blds[buf][br][(kch ^ (br & 7)) * 8];  \
            }                                                                   \
            _Pragma("unroll") for (int mi = 0; mi < 4; ++mi)                    \
                _Pragma("unroll") for (int ni = 0; ni < 4; ++ni)                \
                    acc[mi][ni] = mfma_bf16(af[mi], bfr[ni], acc[mi][ni]);      \
        }                                                                       \
    }

    if constexpr (DBUF == 0) {
        for (int k0 = kbeg; k0 < kend; k0 += 64) {
            STAGE(0, k0);
            __syncthreads();
            COMPUTE(0);
            __syncthreads();
        }
    } else {
        STAGE(0, kbeg);
        for (int k0 = kbeg; k0 < kend; k0 += 64) {
            const int cur = ((k0 - kbeg) >> 6) & 1;
            if (k0 + 64 < kend) {
                STAGE(cur ^ 1, k0 + 64);
                asm volatile("s_waitcnt vmcnt(8)" ::: "memory");
            } else {
                asm volatile("s_waitcnt vmcnt(0)" ::: "memory");
            }
            __builtin_amdgcn_sched_barrier(0);
            __builtin_amdgcn_s_barrier();
            __builtin_amdgcn_sched_barrier(0);
            COMPUTE(cur);
            __builtin_amdgcn_s_barrier();
        }
    }
#undef STAGE
#undef COMPUTE

    const int m0 = bm + wr * 64, n0 = bn + wc * 64;
#pragma unroll
    for (int mi = 0; mi < 4; ++mi) {
#pragma unroll
        for (int ni = 0; ni < 4; ++ni) {
            if constexpr (MODE == 0) {
                const int n = n0 + ni * 16 + l15;
                const int which = n >> 10;
                const int hh = (n >> 6) & 15, d = n & 63;
                const int mbase = m0 + mi * 16 + 4 * lg;
                const int bb = mbase >> 11, t = mbase & 2047;
                if (which == 2) {
                    uint2 pv;
                    pv.x = cvtpk(acc[mi][ni][0], acc[mi][ni][1]);
                    pv.y = cvtpk(acc[mi][ni][2], acc[mi][ni][3]);
                    *(uint2*)(vt + (((size_t)(bb * NH + hh)) * DH + d) * TT + t) = pv;
                } else {
                    u16* dst = which == 0 ? oq : ok;
                    const float sc = which == 0 ? 0.18033688f : 1.0f;  // (1/8)*log2(e)
                    const unsigned p01 = cvtpk(acc[mi][ni][0] * sc, acc[mi][ni][1] * sc);
                    const unsigned p23 = cvtpk(acc[mi][ni][2] * sc, acc[mi][ni][3] * sc);
                    u16* db = dst + (((size_t)(bb * NH + hh)) * TT + t) * DH + d;
                    db[0] = (u16)p01;
                    db[DH] = (u16)(p01 >> 16);
                    db[2 * DH] = (u16)p23;
                    db[3 * DH] = (u16)(p23 >> 16);
                }
            } else if constexpr (MODE == 2) {
                const int n = n0 + ni * 16 + l15;
                const float bn_ = bias[n];
                const float g0 = gelu_fast(acc[mi][ni][0] + bn_);
                const float g1 = gelu_fast(acc[mi][ni][1] + bn_);
                const float g2 = gelu_fast(acc[mi][ni][2] + bn_);
                const float g3 = gelu_fast(acc[mi][ni][3] + bn_);
                const unsigned p01 = cvtpk(g0, g1);
                const unsigned p23 = cvtpk(g2, g3);
                u16* db = outbf + (size_t)(m0 + mi * 16 + 4 * lg) * N + n;
                db[0] = (u16)p01;
                db[N] = (u16)(p01 >> 16);
                db[2 * N] = (u16)p23;
                db[3 * N] = (u16)(p23 >> 16);
            } else {
#pragma unroll
                for (int r = 0; r < 4; ++r) {
                    int m = m0 + mi * 16 + 4 * lg + r;
                    int n = n0 + ni * 16 + l15;
                    float v = acc[mi][ni][r];
                    size_t o = (size_t)m * N + n;
                    if constexpr (MODE == 1) {
                        outf[o] = resid[o] + v;
                    } else {
                        if (SPLIT && ks == 1)
                            part[o] = v;
                        else
                            outf[o] = resid[o] + v + bias[n];
                    }
                }
            }
        }
    }
}

// ---------------- flash attention, causal, swapped-operand MFMA ----------------
// Fixed-reference softmax (no running max: LN'd inputs bound |S'| << fp32/bf16 range;
// masked = -1e30 -> exp2 -> 0; scale cancels in O/l). Unroll-2 KV pipeline over a
// 4-slot LDS ring with adaptive counted vmcnt: softmax(i+1) VALU overlaps PV(i) MFMA.
__global__ __launch_bounds__(256) void attn_kernel(const u16* __restrict__ Q,
                                                   const u16* __restrict__ Kg,
                                                   const u16* __restrict__ Vtg,
                                                   u16* __restrict__ O) {
    __shared__ __align__(16) u16 Klds[4][64][64];
    __shared__ __align__(16) u16 Vlds[4][64][64];
    const int tid = threadIdx.x, lane = tid & 63, w = tid >> 6;
    const int l15 = lane & 15, lg = lane >> 4;

    int id = blockIdx.x + (blockIdx.y << 4);
    int sw = (id & 7) * 64 + (id >> 3);  // XCD k -> heads 4k..4k+3
    const int p = sw & 15, bh = sw >> 4;
    const size_t base = (size_t)bh * TT * DH;
    const int b = bh >> 4, hh = bh & 15;

    const int srow = tid >> 3, pch = tid & 7;
    const int lc = pch ^ (srow & 7);

    const int src0 = (((2 * lg) & 3) << 4) | l15;
    const int src1 = src0 + 16;
    const bool hi = (lg >> 1) != 0;

#define ASTAGE(buf, kv)                                                                     \
    {                                                                                       \
        gload_lds16(Kg + base + (size_t)((kv) * 64 + srow) * DH + lc * 8,                   \
                    &Klds[buf][srow][pch * 8]);                                             \
        gload_lds16(Kg + base + (size_t)((kv) * 64 + srow + 32) * DH + lc * 8,              \
                    &Klds[buf][srow + 32][pch * 8]);                                        \
        gload_lds16(Vtg + base + (size_t)srow * TT + (kv) * 64 + lc * 8,                    \
                    &Vlds[buf][srow][pch * 8]);                                             \
        gload_lds16(Vtg + base + (size_t)(srow + 32) * TT + (kv) * 64 + lc * 8,             \
                    &Vlds[buf][srow + 32][pch * 8]);                                        \
    }

    for (int half = 0; half < 2; ++half) {
        const int qt = half ? (31 - p) : p;
        const int nkv = qt + 1;
        const int qrow = qt * 64 + w * 16 + l15;
        uint4 qu0 = *(const uint4*)(Q + base + (size_t)qrow * DH + 8 * lg);
        uint4 qu1 = *(const uint4*)(Q + base + (size_t)qrow * DH + 32 + 8 * lg);
        asm volatile("" : "+v"(qu0.x), "+v"(qu0.y), "+v"(qu0.z), "+v"(qu0.w),
                          "+v"(qu1.x), "+v"(qu1.y), "+v"(qu1.z), "+v"(qu1.w));
        const bf16x8 qf0 = *(const bf16x8*)&qu0;
        const bf16x8 qf1 = *(const bf16x8*)&qu1;

        f32x4 o[4] = {};
        float lsum = 0.0f;

        auto compute_tile = [&](int buf, bool masked, int kvi) {
            // S^T = K Q^T
            f32x4 s[4] = {};
            __builtin_amdgcn_s_setprio(1);
#pragma unroll
            for (int nf = 0; nf < 4; ++nf) {
                const int row = nf * 16 + l15;
                bf16x8 kb0 = *(const bf16x8*)&Klds[buf][row][(lg ^ (l15 & 7)) * 8];
                bf16x8 kb1 = *(const bf16x8*)&Klds[buf][row][((4 + lg) ^ (l15 & 7)) * 8];
                s[nf] = mfma_bf16(kb0, qf0, s[nf]);
                s[nf] = mfma_bf16(kb1, qf1, s[nf]);
            }
            __builtin_amdgcn_s_setprio(0);

            if (masked) {  // diagonal tile: causal mask
#pragma unroll
                for (int nf = 0; nf < 4; ++nf) {
                    const int tg = kvi * 64 + nf * 16 + 4 * lg;
#pragma unroll
                    for (int r = 0; r < 4; ++r)
                        if (tg + r > qrow) s[nf][r] = -1e30f;
                }
            }

            // fixed-reference softmax: P = exp2(S') directly
            float ps = 0.0f;
#pragma unroll
            for (int nf = 0; nf < 4; ++nf) {
#pragma unroll
                for (int r = 0; r < 4; ++r) {
                    const float pp = exp2f(s[nf][r]);
                    s[nf][r] = pp;
                    ps += pp;
                }
            }
            lsum += ps;

            // pack P rows to bf16 and redistribute into PV B-fragments
            unsigned pk[4][2];
#pragma unroll
            for (int nf = 0; nf < 4; ++nf) {
                pk[nf][0] = cvtpk(s[nf][0], s[nf][1]);
                pk[nf][1] = cvtpk(s[nf][2], s[nf][3]);
            }
            bf16x8 pa[2];
#pragma unroll
            for (int kf = 0; kf < 2; ++kf) {
                unsigned a0 = __shfl((int)pk[2 * kf][0], src0);
                unsigned a1 = __shfl((int)pk[2 * kf][1], src0);
                unsigned a2 = __shfl((int)pk[2 * kf][0], src1);
                unsigned a3 = __shfl((int)pk[2 * kf][1], src1);
                unsigned c0 = __shfl((int)pk[2 * kf + 1][0], src0);
                unsigned c1 = __shfl((int)pk[2 * kf + 1][1], src0);
                unsigned c2 = __shfl((int)pk[2 * kf + 1][0], src1);
                unsigned c3 = __shfl((int)pk[2 * kf + 1][1], src1);
                uint4 wv;
                wv.x = hi ? c0 : a0;
                wv.y = hi ? c1 : a1;
                wv.z = hi ? c2 : a2;
                wv.w = hi ? c3 : a3;
                pa[kf] = *(const bf16x8*)&wv;
            }

            // O^T += V^T P^T
            __builtin_amdgcn_s_setprio(1);
#pragma unroll
            for (int nf = 0; nf < 4; ++nf) {
                const int row = nf * 16 + l15;
                bf16x8 vb0 = *(const bf16x8*)&Vlds[buf][row][(lg ^ (l15 & 7)) * 8];
                bf16x8 vb1 = *(const bf16x8*)&Vlds[buf][row][((4 + lg) ^ (l15 & 7)) * 8];
                o[nf] = mfma_bf16(vb0, pa[0], o[nf]);
                o[nf] = mfma_bf16(vb1, pa[1], o[nf]);
            }
            __builtin_amdgcn_s_setprio(0);
        };

        // prologue: stage tiles 0,1
        ASTAGE(0, 0);
        if (nkv > 1) ASTAGE(1, 1);

        for (int kv = 0; kv < nkv; kv += 2) {
            int nst = 0;
            if (kv + 2 < nkv) { ASTAGE((kv + 2) & 3, kv + 2); nst += 4; }
            if (kv + 3 < nkv) { ASTAGE((kv + 3) & 3, kv + 3); nst += 4; }
            if (nst == 8)
                asm volatile("s_waitcnt vmcnt(8)" ::: "memory");
            else if (nst == 4)
                asm volatile("s_waitcnt vmcnt(4)" ::: "memory");
            else
                asm volatile("s_waitcnt vmcnt(0)" ::: "memory");
            __builtin_amdgcn_sched_barrier(0);
            __builtin_amdgcn_s_barrier();
            __builtin_amdgcn_sched_barrier(0);

            compute_tile(kv & 3, kv == qt, kv);
            if (kv + 1 < nkv) compute_tile((kv + 1) & 3, kv + 1 == qt, kv + 1);

            __builtin_amdgcn_s_barrier();
        }

        lsum += __shfl_xor(lsum, 16);
        lsum += __shfl_xor(lsum, 32);
        const float linv = 1.0f / lsum;
#pragma unroll
        for (int nf = 0; nf < 4; ++nf) {
            uint2 pv;
            pv.x = cvtpk(o[nf][0] * linv, o[nf][1] * linv);
            pv.y = cvtpk(o[nf][2] * linv, o[nf][3] * linv);
            *(uint2*)(O + ((size_t)b * TT + qrow) * DM + hh * DH + nf * 16 + 4 * lg) = pv;
        }
    }
#undef ASTAGE
}

extern "C" void kernel_launch(void* const* d_in, const int* in_sizes, int n_in,
                              void* d_out, int out_size, void* d_ws, size_t ws_size,
                              hipStream_t stream) {
    const float* x = (const float*)d_in[0];
    const float* wqkv = (const float*)d_in[1];
    const float* wout = (const float*)d_in[2];
    const float* ln1g = (const float*)d_in[3];
    const float* ln1b = (const float*)d_in[4];
    const float* ln2g = (const float*)d_in[5];
    const float* ln2b = (const float*)d_in[6];
    const float* w1 = (const float*)d_in[7];
    const float* b1 = (const float*)d_in[8];
    const float* w2 = (const float*)d_in[9];
    const float* b2 = (const float*)d_in[10];
    float* out = (float*)d_out;
    char* ws = (char*)d_ws;

    u16* wqkv_t = (u16*)(ws + 0);          // [3072][1024] bf16 (dead by FF2)
    u16* wout_t = (u16*)(ws + 6291456);    // [1024][1024]      (dead by FF2)
    u16* w1_t   = (u16*)(ws + 8388608);    // [4096][1024]      (dead by FF2)
    u16* w2_t   = (u16*)(ws + 16777216);   // [1024][4096]
    u16* h_bf   = (u16*)(ws + 25165824);   // [4096][1024] (LN1, reused for LN2)
    u16* q_bf   = (u16*)(ws + 33554432);   // [B,H,T,Dh]
    u16* k_bf   = (u16*)(ws + 41943040);   // [B,H,T,Dh]
    u16* vt_bf  = (u16*)(ws + 50331648);   // [B,H,Dh,T]  (V^T)
    u16* at_bf  = (u16*)(ws + 58720256);   // [4096][1024]
    float* x1   = (float*)(ws + 67108864); // [4096][1024] fp32
    u16* ff1_bf = q_bf;                    // aliases q/k/vt/at (dead by FF1): [4096][4096]
    float* p1   = (float*)(ws + 0);        // FF2 K-half-1 partial [4096][1024] fp32 (16 MB)

    transW<<<dim3(96, 32), 256, 0, stream>>>(wqkv, wqkv_t, 1024, 3072);
    transW<<<dim3(32, 32), 256, 0, stream>>>(wout, wout_t, 1024, 1024);
    transW<<<dim3(128, 32), 256, 0, stream>>>(w1, w1_t, 1024, 4096);
    transW<<<dim3(32, 128), 256, 0, stream>>>(w2, w2_t, 4096, 1024);

    ln_kernel<<<4096, 256, 0, stream>>>(x, ln1g, ln1b, h_bf);

    gemm_kernel<0, 1, 0><<<dim3(24, 32), 256, 0, stream>>>(h_bf, wqkv_t, 4096, 3072, 1024,
                                                           q_bf, k_bf, vt_bf,
                                                           nullptr, nullptr, nullptr, nullptr,
                                                           nullptr);

    attn_kernel<<<dim3(16, 32), 256, 0, stream>>>(q_bf, k_bf, vt_bf, at_bf);

    gemm_kernel<1, 1, 0><<<dim3(8, 32), 256, 0, stream>>>(at_bf, wout_t, 4096, 1024, 1024,
                                                          nullptr, nullptr, nullptr,
                                                          x, x1, nullptr, nullptr, nullptr);

    ln_kernel<<<4096, 256, 0, stream>>>(x1, ln2g, ln2b, h_bf);

    gemm_kernel<2, 1, 0><<<dim3(32, 32), 256, 0, stream>>>(h_bf, w1_t, 4096, 4096, 1024,
                                                           nullptr, nullptr, nullptr,
                                                           nullptr, nullptr, b1, ff1_bf,
                                                           nullptr);

    gemm_kernel<3, 1, 1><<<dim3(8, 64), 256, 0, stream>>>(ff1_bf, w2_t, 4096, 1024, 4096,
                                                          nullptr, nullptr, nullptr,
                                                          x1, out, b2, nullptr, p1);

    add_kernel<<<2048, 256, 0, stream>>>(out, p1, 4096 * 1024 / 4);
}

// Round 8
// 241.667 us; speedup vs baseline: 1.5600x; 1.0120x over previous
//
#include <hip/hip_runtime.h>
#include <hip/hip_bf16.h>
#include <cstdint>

#define DM 1024
#define DFF 4096
#define NB 2
#define TT 2048
#define NH 16
#define DH 64

typedef unsigned short u16;
typedef __bf16 bf16x8 __attribute__((ext_vector_type(8)));
typedef float f32x4 __attribute__((ext_vector_type(4)));

__device__ __forceinline__ u16 f2b(float f) {
    union { float f; unsigned u; } v; v.f = f;
    unsigned u = v.u;
    return (u16)((u + 0x7FFFu + ((u >> 16) & 1u)) >> 16);
}

__device__ __forceinline__ unsigned cvtpk(float a, float b) {
    unsigned r;
    asm("v_cvt_pk_bf16_f32 %0, %1, %2" : "=v"(r) : "v"(a), "v"(b));
    return r;
}

// gelu(z) = z * sigmoid(2*0.79788456*(z+0.044715 z^3)); exp2-based, ~7 VALU ops.
__device__ __forceinline__ float gelu_fast(float z) {
    const float u = z * z;
    const float w = z * __builtin_fmaf(u, 0.10294324f, 2.3022082f);
    const float e = exp2f(w);
    const float r = __builtin_amdgcn_rcpf(1.0f + e);
    return z - z * r;
}

__device__ __forceinline__ f32x4 mfma_bf16(bf16x8 a, bf16x8 b, f32x4 c) {
    return __builtin_amdgcn_mfma_f32_16x16x32_bf16(a, b, c, 0, 0, 0);
}

__device__ __forceinline__ void gload_lds16(const void* g, void* l) {
    __builtin_amdgcn_global_load_lds((const __attribute__((address_space(1))) unsigned int*)g,
                                     (__attribute__((address_space(3))) unsigned int*)l, 16, 0, 0);
}

// ---------------- transpose + fp32->bf16 convert: Wt[n][k] = bf16(W[k][n]) ----------------
__global__ __launch_bounds__(256) void transW(const float* __restrict__ W, u16* __restrict__ Wt,
                                              int K, int N) {
    __shared__ float t[32][33];
    int tx = threadIdx.x & 31, ty = threadIdx.x >> 5;
    int k0 = blockIdx.y * 32, n0 = blockIdx.x * 32;
#pragma unroll
    for (int j = 0; j < 4; ++j)
        t[ty + 8 * j][tx] = W[(size_t)(k0 + ty + 8 * j) * N + n0 + tx];
    __syncthreads();
#pragma unroll
    for (int j = 0; j < 4; ++j)
        Wt[(size_t)(n0 + ty + 8 * j) * K + k0 + tx] = f2b(t[tx][ty + 8 * j]);
}

// ---------------- LayerNorm fp32 -> bf16 ----------------
__global__ __launch_bounds__(256) void ln_kernel(const float* __restrict__ X,
                                                 const float* __restrict__ g,
                                                 const float* __restrict__ bt,
                                                 u16* __restrict__ H) {
    int row = blockIdx.x, tid = threadIdx.x;
    float4 v = ((const float4*)(X + (size_t)row * DM))[tid];
    float s = v.x + v.y + v.z + v.w;
    float ss = v.x * v.x + v.y * v.y + v.z * v.z + v.w * v.w;
#pragma unroll
    for (int off = 32; off >= 1; off >>= 1) {
        s += __shfl_xor(s, off);
        ss += __shfl_xor(ss, off);
    }
    __shared__ float sb[8];
    int w = tid >> 6, lane = tid & 63;
    if (lane == 0) { sb[w] = s; sb[4 + w] = ss; }
    __syncthreads();
    s = sb[0] + sb[1] + sb[2] + sb[3];
    ss = sb[4] + sb[5] + sb[6] + sb[7];
    float mu = s * (1.0f / DM);
    float var = ss * (1.0f / DM) - mu * mu;
    float rstd = rsqrtf(var + 1e-5f);
    float4 gv = ((const float4*)g)[tid];
    float4 bv = ((const float4*)bt)[tid];
    uint2 hv;
    hv.x = cvtpk((v.x - mu) * rstd * gv.x + bv.x, (v.y - mu) * rstd * gv.y + bv.y);
    hv.y = cvtpk((v.z - mu) * rstd * gv.z + bv.z, (v.w - mu) * rstd * gv.w + bv.w);
    ((uint2*)(H + (size_t)row * DM))[tid] = hv;
}

// ---------------- elementwise add: out += part ----------------
__global__ __launch_bounds__(256) void add_kernel(float* __restrict__ out,
                                                  const float* __restrict__ part, int n4) {
    int idx = blockIdx.x * 256 + threadIdx.x;
    const int stride = gridDim.x * 256;
    for (; idx < n4; idx += stride) {
        float4 a = ((const float4*)out)[idx];
        float4 p = ((const float4*)part)[idx];
        a.x += p.x; a.y += p.y; a.z += p.z; a.w += p.w;
        ((float4*)out)[idx] = a;
    }
}

// ================= 256x256 8-phase GEMM (T2+T3+T4+T5) =================
// 512 threads = 8 waves (2M x 4N); BK=64; per-wave C = 128x64 (8x4 16x16 frags).
// LDS 128 KB: A/B tiles 2-buffered. Per K-tile 4 phases; stage ledger:
//   ph1: A(t+1)->buf1A   ph2: B(t+2)->buf0B   ph5: A(t+2)->buf0A   ph6: B(t+3)->buf1B
// vmcnt(4) at phases 4 and 8 only (counted prefetch, never drain mid-loop).
// Region deadness: B-buf dead after its phase 1; A-buf dead after its phase 4 --
// every stage issue lands only in dead regions (see ledger in session notes).
// MODE 0: qkv scatter epilogue; MODE 2: gelu(C+bias) bf16.
template <int MODE>
__global__ __launch_bounds__(512, 2) void gemm256(
    const u16* __restrict__ A, const u16* __restrict__ Bt, int M, int N, int K,
    u16* __restrict__ oq, u16* __restrict__ ok, u16* __restrict__ vt,
    const float* __restrict__ bias, u16* __restrict__ outbf) {
    __shared__ __align__(16) u16 Alds[2][256][64];
    __shared__ __align__(16) u16 Blds[2][256][64];
    const int tid = threadIdx.x;
    const int lane = tid & 63, w = tid >> 6;
    const int wm = w >> 2, wn = w & 3;
    const int l15 = lane & 15, lg = lane >> 4;
    int bid = blockIdx.x + gridDim.x * blockIdx.y;
    const int nwg = gridDim.x * gridDim.y;
    bid = (bid & 7) * (nwg >> 3) + (bid >> 3);
    const int bm = (bid / gridDim.x) * 256, bn = (bid % gridDim.x) * 256;
    const int srow = tid >> 3, pch = tid & 7;
    const int lc = pch ^ (srow & 7);

    const u16* Ap = A + (size_t)(bm + srow) * K + lc * 8;
    const u16* Bp = Bt + (size_t)(bn + srow) * K + lc * 8;

    f32x4 acc[8][4] = {};
    bf16x8 bf[4][2];
    const int NT = K >> 6;  // assumed even, >= 2

#define SA256(buf, t)                                                           \
    {                                                                           \
        _Pragma("unroll") for (int j = 0; j < 4; ++j)                           \
            gload_lds16(Ap + (size_t)(64 * j) * K + (t) * 64,                   \
                        &Alds[buf][srow + 64 * j][pch * 8]);                    \
    }
#define SB256(buf, t)                                                           \
    {                                                                           \
        _Pragma("unroll") for (int j = 0; j < 4; ++j)                           \
            gload_lds16(Bp + (size_t)(64 * j) * K + (t) * 64,                   \
                        &Blds[buf][srow + 64 * j][pch * 8]);                    \
    }

#define PHASE(BUF, P, STAGE, WAIT)                                              \
    {                                                                           \
        bf16x8 af[2][2];                                                        \
        _Pragma("unroll") for (int i = 0; i < 2; ++i) {                         \
            const int row = wm * 128 + (2 * (P) + i) * 16 + l15;                \
            _Pragma("unroll") for (int ks = 0; ks < 2; ++ks)                    \
                af[i][ks] =                                                     \
                    *(const bf16x8*)&Alds[BUF][row][((ks * 4 + lg) ^ (row & 7)) * 8]; \
        }                                                                       \
        if constexpr ((P) == 0) {                                               \
            _Pragma("unroll") for (int nf = 0; nf < 4; ++nf) {                  \
                const int row = wn * 64 + nf * 16 + l15;                        \
                _Pragma("unroll") for (int ks = 0; ks < 2; ++ks)                \
                    bf[nf][ks] =                                                \
                        *(const bf16x8*)&Blds[BUF][row][((ks * 4 + lg) ^ (row & 7)) * 8]; \
            }                                                                   \
        }                                                                       \
        STAGE;                                                                  \
        WAIT;                                                                   \
        __builtin_amdgcn_s_barrier();                                           \
        asm volatile("s_waitcnt lgkmcnt(0)" ::: "memory");                      \
        __builtin_amdgcn_sched_barrier(0);                                      \
        __builtin_amdgcn_s_setprio(1);                                          \
        _Pragma("unroll") for (int i = 0; i < 2; ++i)                           \
            _Pragma("unroll") for (int nf = 0; nf < 4; ++nf)                    \
                _Pragma("unroll") for (int ks = 0; ks < 2; ++ks)                \
                    acc[2 * (P) + i][nf] =                                      \
                        mfma_bf16(af[i][ks], bf[nf][ks], acc[2 * (P) + i][nf]); \
        __builtin_amdgcn_s_setprio(0);                                          \
        __builtin_amdgcn_s_barrier();                                           \
    }

    // prologue: B(0), A(0), B(1); wait for B0/A0 (4 newest = B1 may fly); barrier
    SB256(0, 0);
    SA256(0, 0);
    SB256(1, 1);
    asm volatile("s_waitcnt vmcnt(4)" ::: "memory");
    __builtin_amdgcn_sched_barrier(0);
    __builtin_amdgcn_s_barrier();

    for (int it = 0; it < (NT >> 1); ++it) {
        const int t0 = 2 * it;
        const bool more = (t0 + 2 < NT);
        // ---- K-tile t0 in buf0 ----
        PHASE(0, 0, { SA256(1, t0 + 1); }, {});
        PHASE(0, 1, { if (more) SB256(0, t0 + 2); }, {});
        PHASE(0, 2, {}, {});
        PHASE(0, 3, {}, {
            if (more) { asm volatile("s_waitcnt vmcnt(4)" ::: "memory"); }
            else { asm volatile("s_waitcnt vmcnt(0)" ::: "memory"); }
            __builtin_amdgcn_sched_barrier(0);
        });
        // ---- K-tile t0+1 in buf1 ----
        PHASE(1, 0, { if (more) SA256(0, t0 + 2); }, {});
        PHASE(1, 1, { if (more) SB256(1, t0 + 3); }, {});
        PHASE(1, 2, {}, {});
        PHASE(1, 3, {}, {
            if (more) {
                asm volatile("s_waitcnt vmcnt(4)" ::: "memory");
                __builtin_amdgcn_sched_barrier(0);
            }
        });
    }
#undef PHASE
#undef SA256
#undef SB256

    const int m0 = bm + wm * 128, n0 = bn + wn * 64;
#pragma unroll
    for (int mi = 0; mi < 8; ++mi) {
#pragma unroll
        for (int ni = 0; ni < 4; ++ni) {
            if constexpr (MODE == 0) {
                const int n = n0 + ni * 16 + l15;
                const int which = n >> 10;
                const int hh = (n >> 6) & 15, d = n & 63;
                const int mbase = m0 + mi * 16 + 4 * lg;
                const int bb = mbase >> 11, t = mbase & 2047;
                if (which == 2) {
                    uint2 pv;
                    pv.x = cvtpk(acc[mi][ni][0], acc[mi][ni][1]);
                    pv.y = cvtpk(acc[mi][ni][2], acc[mi][ni][3]);
                    *(uint2*)(vt + (((size_t)(bb * NH + hh)) * DH + d) * TT + t) = pv;
                } else {
                    u16* dst = which == 0 ? oq : ok;
                    const float sc = which == 0 ? 0.18033688f : 1.0f;  // (1/8)*log2(e)
                    const unsigned p01 = cvtpk(acc[mi][ni][0] * sc, acc[mi][ni][1] * sc);
                    const unsigned p23 = cvtpk(acc[mi][ni][2] * sc, acc[mi][ni][3] * sc);
                    u16* db = dst + (((size_t)(bb * NH + hh)) * TT + t) * DH + d;
                    db[0] = (u16)p01;
                    db[DH] = (u16)(p01 >> 16);
                    db[2 * DH] = (u16)p23;
                    db[3 * DH] = (u16)(p23 >> 16);
                }
            } else {
                const int n = n0 + ni * 16 + l15;
                const float bn_ = bias[n];
                const float g0 = gelu_fast(acc[mi][ni][0] + bn_);
                const float g1 = gelu_fast(acc[mi][ni][1] + bn_);
                const float g2 = gelu_fast(acc[mi][ni][2] + bn_);
                const float g3 = gelu_fast(acc[mi][ni][3] + bn_);
                const unsigned p01 = cvtpk(g0, g1);
                const unsigned p23 = cvtpk(g2, g3);
                u16* db = outbf + (size_t)(m0 + mi * 16 + 4 * lg) * N + n;
                db[0] = (u16)p01;
                db[N] = (u16)(p01 >> 16);
                db[2 * N] = (u16)p23;
                db[3 * N] = (u16)(p23 >> 16);
            }
        }
    }
}

// ---------------- 128x128 bf16 MFMA GEMM (wout / FF2-splitK) ----------------
template <int MODE, int DBUF, int SPLIT>
__global__ __launch_bounds__(256) void gemm_kernel(
    const u16* __restrict__ A, const u16* __restrict__ Bt, int M, int N, int K,
    u16* __restrict__ oq, u16* __restrict__ ok, u16* __restrict__ vt,
    const float* __restrict__ resid, float* __restrict__ outf,
    const float* __restrict__ bias, u16* __restrict__ outbf,
    float* __restrict__ part) {
    __shared__ __align__(16) u16 Alds[DBUF + 1][128][64];
    __shared__ __align__(16) u16 Blds[DBUF + 1][128][64];
    const int tid = threadIdx.x;
    const int lane = tid & 63;
    const int w = tid >> 6;
    const int wr = w >> 1, wc = w & 1;
    int bid = blockIdx.x + gridDim.x * blockIdx.y;
    const int nwg = gridDim.x * gridDim.y;
    bid = (bid & 7) * (nwg >> 3) + (bid >> 3);
    int mrow = bid / gridDim.x;
    int ks = 0;
    if constexpr (SPLIT) {
        const int mtiles = (nwg / gridDim.x) >> 1;
        ks = mrow >= mtiles;
        mrow -= ks * mtiles;
    }
    const int bm = mrow * 128, bn = (bid % gridDim.x) * 128;
    const int kbeg = SPLIT ? ks * (K >> 1) : 0;
    const int kend = SPLIT ? kbeg + (K >> 1) : K;
    const int l15 = lane & 15, lg = lane >> 4;
    const int srow = tid >> 3, pch = tid & 7;
    const int lc = pch ^ (srow & 7);

    f32x4 acc[4][4] = {};
    const u16* Ap = A + (size_t)(bm + srow) * K + lc * 8;
    const u16* Bp = Bt + (size_t)(bn + srow) * K + lc * 8;

#define STAGE(buf, k0)                                                          \
    {                                                                           \
        _Pragma("unroll") for (int i = 0; i < 4; ++i) {                         \
            gload_lds16(Ap + (size_t)(32 * i) * K + (k0), &Alds[buf][srow + 32 * i][pch * 8]); \
            gload_lds16(Bp + (size_t)(32 * i) * K + (k0), &Blds[buf][srow + 32 * i][pch * 8]); \
        }                                                                       \
    }

#define COMPUTE(buf)                                                            \
    {                                                                           \
        _Pragma("unroll") for (int kk = 0; kk < 2; ++kk) {                      \
            bf16x8 af[4], bfr[4];                                               \
            _Pragma("unroll") for (int f = 0; f < 4; ++f) {                     \
                const int ar = wr * 64 + f * 16 + l15;                          \
                const int br = wc * 64 + f * 16 + l15;                          \
                const int kch = kk * 4 + lg;                                    \
                af[f] = *(const bf16x8*)&Alds[buf][ar][(kch ^ (ar & 7)) * 8];   \
                bfr[f] = *(const bf16x8*)&Blds[buf][br][(kch ^ (br & 7)) * 8];  \
            }                                                                   \
            _Pragma("unroll") for (int mi = 0; mi < 4; ++mi)                    \
                _Pragma("unroll") for (int ni = 0; ni < 4; ++ni)                \
                    acc[mi][ni] = mfma_bf16(af[mi], bfr[ni], acc[mi][ni]);      \
        }                                                                       \
    }

    if constexpr (DBUF == 0) {
        for (int k0 = kbeg; k0 < kend; k0 += 64) {
            STAGE(0, k0);
            __syncthreads();
            COMPUTE(0);
            __syncthreads();
        }
    } else {
        STAGE(0, kbeg);
        for (int k0 = kbeg; k0 < kend; k0 += 64) {
            const int cur = ((k0 - kbeg) >> 6) & 1;
            if (k0 + 64 < kend) {
                STAGE(cur ^ 1, k0 + 64);
                asm volatile("s_waitcnt vmcnt(8)" ::: "memory");
            } else {
                asm volatile("s_waitcnt vmcnt(0)" ::: "memory");
            }
            __builtin_amdgcn_sched_barrier(0);
            __builtin_amdgcn_s_barrier();
            __builtin_amdgcn_sched_barrier(0);
            COMPUTE(cur);
            __builtin_amdgcn_s_barrier();
        }
    }
#undef STAGE
#undef COMPUTE

    const int m0 = bm + wr * 64, n0 = bn + wc * 64;
#pragma unroll
    for (int mi = 0; mi < 4; ++mi) {
#pragma unroll
        for (int ni = 0; ni < 4; ++ni) {
            if constexpr (MODE == 0) {
                const int n = n0 + ni * 16 + l15;
                const int which = n >> 10;
                const int hh = (n >> 6) & 15, d = n & 63;
                const int mbase = m0 + mi * 16 + 4 * lg;
                const int bb = mbase >> 11, t = mbase & 2047;
                if (which == 2) {
                    uint2 pv;
                    pv.x = cvtpk(acc[mi][ni][0], acc[mi][ni][1]);
                    pv.y = cvtpk(acc[mi][ni][2], acc[mi][ni][3]);
                    *(uint2*)(vt + (((size_t)(bb * NH + hh)) * DH + d) * TT + t) = pv;
                } else {
                    u16* dst = which == 0 ? oq : ok;
                    const float sc = which == 0 ? 0.18033688f : 1.0f;
                    const unsigned p01 = cvtpk(acc[mi][ni][0] * sc, acc[mi][ni][1] * sc);
                    const unsigned p23 = cvtpk(acc[mi][ni][2] * sc, acc[mi][ni][3] * sc);
                    u16* db = dst + (((size_t)(bb * NH + hh)) * TT + t) * DH + d;
                    db[0] = (u16)p01;
                    db[DH] = (u16)(p01 >> 16);
                    db[2 * DH] = (u16)p23;
                    db[3 * DH] = (u16)(p23 >> 16);
                }
            } else if constexpr (MODE == 2) {
                const int n = n0 + ni * 16 + l15;
                const float bn_ = bias[n];
                const float g0 = gelu_fast(acc[mi][ni][0] + bn_);
                const float g1 = gelu_fast(acc[mi][ni][1] + bn_);
                const float g2 = gelu_fast(acc[mi][ni][2] + bn_);
                const float g3 = gelu_fast(acc[mi][ni][3] + bn_);
                const unsigned p01 = cvtpk(g0, g1);
                const unsigned p23 = cvtpk(g2, g3);
                u16* db = outbf + (size_t)(m0 + mi * 16 + 4 * lg) * N + n;
                db[0] = (u16)p01;
                db[N] = (u16)(p01 >> 16);
                db[2 * N] = (u16)p23;
                db[3 * N] = (u16)(p23 >> 16);
            } else {
#pragma unroll
                for (int r = 0; r < 4; ++r) {
                    int m = m0 + mi * 16 + 4 * lg + r;
                    int n = n0 + ni * 16 + l15;
                    float v = acc[mi][ni][r];
                    size_t o = (size_t)m * N + n;
                    if constexpr (MODE == 1) {
                        outf[o] = resid[o] + v;
                    } else {
                        if (SPLIT && ks == 1)
                            part[o] = v;
                        else
                            outf[o] = resid[o] + v + bias[n];
                    }
                }
            }
        }
    }
}

// ---------------- flash attention, causal, swapped-operand MFMA ----------------
__global__ __launch_bounds__(256) void attn_kernel(const u16* __restrict__ Q,
                                                   const u16* __restrict__ Kg,
                                                   const u16* __restrict__ Vtg,
                                                   u16* __restrict__ O) {
    __shared__ __align__(16) u16 Klds[4][64][64];
    __shared__ __align__(16) u16 Vlds[4][64][64];
    const int tid = threadIdx.x, lane = tid & 63, w = tid >> 6;
    const int l15 = lane & 15, lg = lane >> 4;

    int id = blockIdx.x + (blockIdx.y << 4);
    int sw = (id & 7) * 64 + (id >> 3);  // XCD k -> heads 4k..4k+3
    const int p = sw & 15, bh = sw >> 4;
    const size_t base = (size_t)bh * TT * DH;
    const int b = bh >> 4, hh = bh & 15;

    const int srow = tid >> 3, pch = tid & 7;
    const int lc = pch ^ (srow & 7);

    const int src0 = (((2 * lg) & 3) << 4) | l15;
    const int src1 = src0 + 16;
    const bool hi = (lg >> 1) != 0;

#define ASTAGE(buf, kv)                                                                     \
    {                                                                                       \
        gload_lds16(Kg + base + (size_t)((kv) * 64 + srow) * DH + lc * 8,                   \
                    &Klds[buf][srow][pch * 8]);                                             \
        gload_lds16(Kg + base + (size_t)((kv) * 64 + srow + 32) * DH + lc * 8,              \
                    &Klds[buf][srow + 32][pch * 8]);                                        \
        gload_lds16(Vtg + base + (size_t)srow * TT + (kv) * 64 + lc * 8,                    \
                    &Vlds[buf][srow][pch * 8]);                                             \
        gload_lds16(Vtg + base + (size_t)(srow + 32) * TT + (kv) * 64 + lc * 8,             \
                    &Vlds[buf][srow + 32][pch * 8]);                                        \
    }

    for (int half = 0; half < 2; ++half) {
        const int qt = half ? (31 - p) : p;
        const int nkv = qt + 1;
        const int qrow = qt * 64 + w * 16 + l15;
        uint4 qu0 = *(const uint4*)(Q + base + (size_t)qrow * DH + 8 * lg);
        uint4 qu1 = *(const uint4*)(Q + base + (size_t)qrow * DH + 32 + 8 * lg);
        asm volatile("" : "+v"(qu0.x), "+v"(qu0.y), "+v"(qu0.z), "+v"(qu0.w),
                          "+v"(qu1.x), "+v"(qu1.y), "+v"(qu1.z), "+v"(qu1.w));
        const bf16x8 qf0 = *(const bf16x8*)&qu0;
        const bf16x8 qf1 = *(const bf16x8*)&qu1;

        f32x4 o[4] = {};
        float lsum = 0.0f;

        auto compute_tile = [&](int buf, bool masked, int kvi) {
            f32x4 s[4] = {};
            __builtin_amdgcn_s_setprio(1);
#pragma unroll
            for (int nf = 0; nf < 4; ++nf) {
                const int row = nf * 16 + l15;
                bf16x8 kb0 = *(const bf16x8*)&Klds[buf][row][(lg ^ (l15 & 7)) * 8];
                bf16x8 kb1 = *(const bf16x8*)&Klds[buf][row][((4 + lg) ^ (l15 & 7)) * 8];
                s[nf] = mfma_bf16(kb0, qf0, s[nf]);
                s[nf] = mfma_bf16(kb1, qf1, s[nf]);
            }
            __builtin_amdgcn_s_setprio(0);

            if (masked) {
#pragma unroll
                for (int nf = 0; nf < 4; ++nf) {
                    const int tg = kvi * 64 + nf * 16 + 4 * lg;
#pragma unroll
                    for (int r = 0; r < 4; ++r)
                        if (tg + r > qrow) s[nf][r] = -1e30f;
                }
            }

            float ps = 0.0f;
#pragma unroll
            for (int nf = 0; nf < 4; ++nf) {
#pragma unroll
                for (int r = 0; r < 4; ++r) {
                    const float pp = exp2f(s[nf][r]);
                    s[nf][r] = pp;
                    ps += pp;
                }
            }
            lsum += ps;

            unsigned pk[4][2];
#pragma unroll
            for (int nf = 0; nf < 4; ++nf) {
                pk[nf][0] = cvtpk(s[nf][0], s[nf][1]);
                pk[nf][1] = cvtpk(s[nf][2], s[nf][3]);
            }
            bf16x8 pa[2];
#pragma unroll
            for (int kf = 0; kf < 2; ++kf) {
                unsigned a0 = __shfl((int)pk[2 * kf][0], src0);
                unsigned a1 = __shfl((int)pk[2 * kf][1], src0);
                unsigned a2 = __shfl((int)pk[2 * kf][0], src1);
                unsigned a3 = __shfl((int)pk[2 * kf][1], src1);
                unsigned c0 = __shfl((int)pk[2 * kf + 1][0], src0);
                unsigned c1 = __shfl((int)pk[2 * kf + 1][1], src0);
                unsigned c2 = __shfl((int)pk[2 * kf + 1][0], src1);
                unsigned c3 = __shfl((int)pk[2 * kf + 1][1], src1);
                uint4 wv;
                wv.x = hi ? c0 : a0;
                wv.y = hi ? c1 : a1;
                wv.z = hi ? c2 : a2;
                wv.w = hi ? c3 : a3;
                pa[kf] = *(const bf16x8*)&wv;
            }

            __builtin_amdgcn_s_setprio(1);
#pragma unroll
            for (int nf = 0; nf < 4; ++nf) {
                const int row = nf * 16 + l15;
                bf16x8 vb0 = *(const bf16x8*)&Vlds[buf][row][(lg ^ (l15 & 7)) * 8];
                bf16x8 vb1 = *(const bf16x8*)&Vlds[buf][row][((4 + lg) ^ (l15 & 7)) * 8];
                o[nf] = mfma_bf16(vb0, pa[0], o[nf]);
                o[nf] = mfma_bf16(vb1, pa[1], o[nf]);
            }
            __builtin_amdgcn_s_setprio(0);
        };

        ASTAGE(0, 0);
        if (nkv > 1) ASTAGE(1, 1);

        for (int kv = 0; kv < nkv; kv += 2) {
            int nst = 0;
            if (kv + 2 < nkv) { ASTAGE((kv + 2) & 3, kv + 2); nst += 4; }
            if (kv + 3 < nkv) { ASTAGE((kv + 3) & 3, kv + 3); nst += 4; }
            if (nst == 8)
                asm volatile("s_waitcnt vmcnt(8)" ::: "memory");
            else if (nst == 4)
                asm volatile("s_waitcnt vmcnt(4)" ::: "memory");
            else
                asm volatile("s_waitcnt vmcnt(0)" ::: "memory");
            __builtin_amdgcn_sched_barrier(0);
            __builtin_amdgcn_s_barrier();
            __builtin_amdgcn_sched_barrier(0);

            compute_tile(kv & 3, kv == qt, kv);
            if (kv + 1 < nkv) compute_tile((kv + 1) & 3, kv + 1 == qt, kv + 1);

            __builtin_amdgcn_s_barrier();
        }

        lsum += __shfl_xor(lsum, 16);
        lsum += __shfl_xor(lsum, 32);
        const float linv = 1.0f / lsum;
#pragma unroll
        for (int nf = 0; nf < 4; ++nf) {
            uint2 pv;
            pv.x = cvtpk(o[nf][0] * linv, o[nf][1] * linv);
            pv.y = cvtpk(o[nf][2] * linv, o[nf][3] * linv);
            *(uint2*)(O + ((size_t)b * TT + qrow) * DM + hh * DH + nf * 16 + 4 * lg) = pv;
        }
    }
#undef ASTAGE
}

extern "C" void kernel_launch(void* const* d_in, const int* in_sizes, int n_in,
                              void* d_out, int out_size, void* d_ws, size_t ws_size,
                              hipStream_t stream) {
    const float* x = (const float*)d_in[0];
    const float* wqkv = (const float*)d_in[1];
    const float* wout = (const float*)d_in[2];
    const float* ln1g = (const float*)d_in[3];
    const float* ln1b = (const float*)d_in[4];
    const float* ln2g = (const float*)d_in[5];
    const float* ln2b = (const float*)d_in[6];
    const float* w1 = (const float*)d_in[7];
    const float* b1 = (const float*)d_in[8];
    const float* w2 = (const float*)d_in[9];
    const float* b2 = (const float*)d_in[10];
    float* out = (float*)d_out;
    char* ws = (char*)d_ws;

    u16* wqkv_t = (u16*)(ws + 0);          // [3072][1024] bf16 (dead by FF2)
    u16* wout_t = (u16*)(ws + 6291456);    // [1024][1024]      (dead by FF2)
    u16* w1_t   = (u16*)(ws + 8388608);    // [4096][1024]      (dead by FF2)
    u16* w2_t   = (u16*)(ws + 16777216);   // [1024][4096]
    u16* h_bf   = (u16*)(ws + 25165824);   // [4096][1024] (LN1, reused for LN2)
    u16* q_bf   = (u16*)(ws + 33554432);   // [B,H,T,Dh]
    u16* k_bf   = (u16*)(ws + 41943040);   // [B,H,T,Dh]
    u16* vt_bf  = (u16*)(ws + 50331648);   // [B,H,Dh,T]  (V^T)
    u16* at_bf  = (u16*)(ws + 58720256);   // [4096][1024]
    float* x1   = (float*)(ws + 67108864); // [4096][1024] fp32
    u16* ff1_bf = q_bf;                    // aliases q/k/vt/at (dead by FF1): [4096][4096]
    float* p1   = (float*)(ws + 0);        // FF2 K-half-1 partial [4096][1024] fp32 (16 MB)

    transW<<<dim3(96, 32), 256, 0, stream>>>(wqkv, wqkv_t, 1024, 3072);
    transW<<<dim3(32, 32), 256, 0, stream>>>(wout, wout_t, 1024, 1024);
    transW<<<dim3(128, 32), 256, 0, stream>>>(w1, w1_t, 1024, 4096);
    transW<<<dim3(32, 128), 256, 0, stream>>>(w2, w2_t, 4096, 1024);

    ln_kernel<<<4096, 256, 0, stream>>>(x, ln1g, ln1b, h_bf);

    gemm256<0><<<dim3(12, 16), 512, 0, stream>>>(h_bf, wqkv_t, 4096, 3072, 1024,
                                                 q_bf, k_bf, vt_bf, nullptr, nullptr);

    attn_kernel<<<dim3(16, 32), 256, 0, stream>>>(q_bf, k_bf, vt_bf, at_bf);

    gemm_kernel<1, 1, 0><<<dim3(8, 32), 256, 0, stream>>>(at_bf, wout_t, 4096, 1024, 1024,
                                                          nullptr, nullptr, nullptr,
                                                          x, x1, nullptr, nullptr, nullptr);

    ln_kernel<<<4096, 256, 0, stream>>>(x1, ln2g, ln2b, h_bf);

    gemm256<2><<<dim3(16, 16), 512, 0, stream>>>(h_bf, w1_t, 4096, 4096, 1024,
                                                 nullptr, nullptr, nullptr, b1, ff1_bf);

    gemm_kernel<3, 1, 1><<<dim3(8, 64), 256, 0, stream>>>(ff1_bf, w2_t, 4096, 1024, 4096,
                                                          nullptr, nullptr, nullptr,
                                                          x1, out, b2, nullptr, p1);

    add_kernel<<<2048, 256, 0, stream>>>(out, p1, 4096 * 1024 / 4);
}